// Round 5
// baseline (385.453 us; speedup 1.0000x reference)
//
#include <hip/hip_runtime.h>
#include <math.h>

#define B_ 8
#define T_ 2048
#define F_ 256
#define M_TOT (B_ * T_)   // 16384

typedef __attribute__((ext_vector_type(8))) short short8;
typedef __attribute__((ext_vector_type(4))) float floatx4;

// bf16 round-to-nearest-even helpers (finite inputs only)
__device__ __forceinline__ short f2bf(float x) {
    unsigned u = __float_as_uint(x);
    u += 0x7FFF + ((u >> 16) & 1);
    return (short)(u >> 16);
}
__device__ __forceinline__ float bf2f(short s) {
    return __uint_as_float(((unsigned)(unsigned short)s) << 16);
}

// ---------------------------------------------------------------------------
// Kernel 1: fused q/k projection  out = feat @ W^T + b  (fp32)
// ---------------------------------------------------------------------------
__global__ __launch_bounds__(256) void qk_proj(
    const float* __restrict__ feat,
    const float* __restrict__ Wq, const float* __restrict__ bq,
    const float* __restrict__ Wk, const float* __restrict__ bk,
    float* __restrict__ q, float* __restrict__ k)
{
    __shared__ float As[16][64];
    __shared__ float Bs[16][64];

    const int tid = threadIdx.x;
    const int bm  = blockIdx.x;
    const int bn  = blockIdx.y;
    const bool isK = bn >= 4;
    const float* __restrict__ W    = isK ? Wk : Wq;
    const float* __restrict__ bias = isK ? bk : bq;
    float* __restrict__ out        = isK ? k : q;
    const int n0 = (bn & 3) * 64;
    const int m0 = bm * 64;

    const int tx = tid & 15;
    const int ty = tid >> 4;
    const int lr = tid >> 2;
    const int lc = (tid & 3) * 4;

    float acc[4][4] = {};

    for (int k0 = 0; k0 < 256; k0 += 16) {
        float4 a4 = *(const float4*)&feat[(size_t)(m0 + lr) * F_ + k0 + lc];
        float4 b4 = *(const float4*)&W   [(size_t)(n0 + lr) * F_ + k0 + lc];
        __syncthreads();
        As[lc + 0][lr] = a4.x; As[lc + 1][lr] = a4.y;
        As[lc + 2][lr] = a4.z; As[lc + 3][lr] = a4.w;
        Bs[lc + 0][lr] = b4.x; Bs[lc + 1][lr] = b4.y;
        Bs[lc + 2][lr] = b4.z; Bs[lc + 3][lr] = b4.w;
        __syncthreads();
#pragma unroll
        for (int kk = 0; kk < 16; ++kk) {
            float av[4], bv[4];
            *(float4*)av = *(const float4*)&As[kk][ty * 4];
            *(float4*)bv = *(const float4*)&Bs[kk][tx * 4];
#pragma unroll
            for (int i = 0; i < 4; ++i)
#pragma unroll
                for (int j = 0; j < 4; ++j)
                    acc[i][j] += av[i] * bv[j];
        }
    }

    const float4 bias4 = *(const float4*)&bias[n0 + tx * 4];
    const float bb[4] = {bias4.x, bias4.y, bias4.z, bias4.w};
#pragma unroll
    for (int i = 0; i < 4; ++i) {
        const int m = m0 + ty * 4 + i;
        float4 o;
        o.x = acc[i][0] + bb[0];
        o.y = acc[i][1] + bb[1];
        o.z = acc[i][2] + bb[2];
        o.w = acc[i][3] + bb[3];
        *(float4*)&out[(size_t)m * F_ + n0 + tx * 4] = o;
    }
}

// ---------------------------------------------------------------------------
// Kernel 2: per-batch partial column sums of k (score = q . mean(k)) + hlens
// ---------------------------------------------------------------------------
__global__ __launch_bounds__(256) void kpart_kernel(
    const float* __restrict__ k, float* __restrict__ kpart,
    float* __restrict__ out_hlens)
{
    const int c = blockIdx.x;
    const int b = blockIdx.y;
    const int tid = threadIdx.x;
    const float* base = &k[((size_t)b * T_ + c * 64) * F_ + tid];
    float s = 0.f;
#pragma unroll 8
    for (int r = 0; r < 64; ++r) s += base[(size_t)r * F_];
    kpart[((size_t)b * 32 + c) * F_ + tid] = s;
    if (b == 0 && c == 0 && tid < B_) out_hlens[tid] = (float)T_;
}

// ---------------------------------------------------------------------------
// Kernel 3: score[b][t] = q_t . kbar_b
// ---------------------------------------------------------------------------
__global__ __launch_bounds__(256) void score_kernel(
    const float* __restrict__ q, const float* __restrict__ kpart,
    float* __restrict__ out_score)
{
    __shared__ float kbar[256];
    const int tid = threadIdx.x;
    const int b   = blockIdx.x >> 5;
    const int t0s = (blockIdx.x & 31) * 64;

    {
        float s = 0.f;
#pragma unroll 8
        for (int c = 0; c < 32; ++c) s += kpart[((size_t)b * 32 + c) * F_ + tid];
        kbar[tid] = s * (1.0f / (float)T_);
    }
    __syncthreads();

    const int row = t0s + (tid >> 2);
    const int fq  = (tid & 3) * 64;
    const float* qr = &q[((size_t)b * T_ + row) * F_ + fq];
    float s = 0.f;
#pragma unroll
    for (int i = 0; i < 16; ++i) {
        float4 v = *(const float4*)&qr[i * 4];
        s += v.x * kbar[fq + i * 4 + 0] + v.y * kbar[fq + i * 4 + 1]
           + v.z * kbar[fq + i * 4 + 2] + v.w * kbar[fq + i * 4 + 3];
    }
    s += __shfl_xor(s, 1, 64);
    s += __shfl_xor(s, 2, 64);
    if ((tid & 3) == 0) out_score[(size_t)b * T_ + row] = s;
}

// ---------------------------------------------------------------------------
// Kernel 4: pack q,k (fp32) -> MFMA fragment-ordered bf16 hi/lo.
// ---------------------------------------------------------------------------
__global__ __launch_bounds__(256) void pack_qk(
    const float* __restrict__ q, const float* __restrict__ k,
    short* __restrict__ qfh, short* __restrict__ qfl,
    short* __restrict__ kfh, short* __restrict__ kfl)
{
    const int tid  = threadIdx.x;
    const int lane = tid & 63;
    const int t    = blockIdx.x * 4 + (tid >> 6);   // 0..8191
    const int b    = t >> 10;
    const int fc   = (t >> 7) & 7;
    const int r16  = t & 127;

    const size_t srow = (size_t)b * T_ + r16 * 16 + (lane & 15);
    const int    col  = fc * 32 + (lane >> 4) * 8;
    const size_t dst  = (size_t)t * 512 + lane * 8;

    {
        float v[8];
        *(float4*)&v[0] = *(const float4*)&q[srow * F_ + col];
        *(float4*)&v[4] = *(const float4*)&q[srow * F_ + col + 4];
        short8 h, l;
#pragma unroll
        for (int j = 0; j < 8; ++j) {
            short hh = f2bf(v[j]);
            h[j] = hh; l[j] = f2bf(v[j] - bf2f(hh));
        }
        *(short8*)&qfh[dst] = h;
        *(short8*)&qfl[dst] = l;
    }
    {
        float v[8];
        *(float4*)&v[0] = *(const float4*)&k[srow * F_ + col];
        *(float4*)&v[4] = *(const float4*)&k[srow * F_ + col + 4];
        short8 h, l;
#pragma unroll
        for (int j = 0; j < 8; ++j) {
            short hh = f2bf(v[j]);
            h[j] = hh; l[j] = f2bf(v[j] - bf2f(hh));
        }
        *(short8*)&kfh[dst] = h;
        *(short8*)&kfl[dst] = l;
    }
}

// ---------------------------------------------------------------------------
// Kernel 5: pack feat -> B-fragment order for PV (transposed: k-dim=key).
// ---------------------------------------------------------------------------
__global__ __launch_bounds__(256) void pack_feat(
    const float* __restrict__ feat,
    short* __restrict__ ffh, short* __restrict__ ffl)
{
    __shared__ float lds[32][257];
    const int tid = threadIdx.x;
    const int kc  = blockIdx.x;   // 0..63
    const int b   = blockIdx.y;

#pragma unroll
    for (int i = 0; i < 8; ++i) {
        const int lin = i * 256 + tid;
        const int r = lin >> 6, c4 = (lin & 63) * 4;
        float4 v = *(const float4*)&feat[((size_t)b * T_ + kc * 32 + r) * F_ + c4];
        lds[r][c4 + 0] = v.x; lds[r][c4 + 1] = v.y;
        lds[r][c4 + 2] = v.z; lds[r][c4 + 3] = v.w;
    }
    __syncthreads();

    const int lane = tid & 63, g = tid >> 6;
    const int quad = lane >> 4, l15 = lane & 15;
#pragma unroll
    for (int fi = 0; fi < 4; ++fi) {
        const int ft = g + fi * 4;
        short8 h, l;
#pragma unroll
        for (int j = 0; j < 8; ++j) {
            float x = lds[quad * 8 + j][ft * 16 + l15];
            short hh = f2bf(x);
            h[j] = hh; l[j] = f2bf(x - bf2f(hh));
        }
        const size_t dst = (((size_t)b * 16 + ft) * 64 + kc) * 512 + lane * 8;
        *(short8*)&ffh[dst] = h;
        *(short8*)&ffl[dst] = l;
    }
}

// ---------------------------------------------------------------------------
// Kernel 6: fused flash attention, MFMA bf16 hi/lo split-3, split-K over keys.
// 1D grid of 512 blocks, XCD-pinned: batch = blockIdx.x & 7, so all blocks of
// a batch land on one XCD (round-robin dispatch) and its ~6 MB fragment
// working set stays in that XCD's 4 MB L2 slice (hot per-kt slice ~256 KB).
// Writes UNNORMALIZED O partial + per-row l partial; combine kernel finishes.
// Block: 64 queries, 512 threads = 8 waves: wave = (qs 0..3, kh 0..1).
// ---------------------------------------------------------------------------
__global__ __launch_bounds__(512, 4) void attn_mfma(
    const short* __restrict__ qfh, const short* __restrict__ qfl,
    const short* __restrict__ kfh, const short* __restrict__ kfl,
    const short* __restrict__ ffh, const short* __restrict__ ffl,
    float* __restrict__ o0, float* __restrict__ o1,
    float* __restrict__ lpart)
{
    __shared__ float P_lds[64][68];   // pad 68: 16B-aligned rows for b128 reads
    __shared__ float l_lds[2][64];

    const int tid  = threadIdx.x;
    const int wave = tid >> 6, lane = tid & 63;
    const int qs   = wave & 3, kh = wave >> 2;
    const int quad = lane >> 4, l15 = lane & 15;

    const int lid  = blockIdx.x;      // 0..511
    const int b    = lid & 7;         // XCD pin: batch -> XCD
    const int qt   = (lid >> 3) & 31; // q-tile within batch
    const int ks   = lid >> 8;        // split-K half
    const int qt16 = qt * 4 + qs;

    // persistent Q fragments (A-operand), hi/lo: 64 VGPRs
    short8 qh[8], ql[8];
#pragma unroll
    for (int fc = 0; fc < 8; ++fc) {
        const size_t off = ((size_t)(b * 8 + fc) * 128 + qt16) * 512 + lane * 8;
        qh[fc] = *(const short8*)&qfh[off];
        ql[fc] = *(const short8*)&qfl[off];
    }

    floatx4 O[8];
#pragma unroll
    for (int i = 0; i < 8; ++i) O[i] = (floatx4){0.f, 0.f, 0.f, 0.f};
    float lsum[4] = {0.f, 0.f, 0.f, 0.f};

    for (int kt = ks * 16; kt < ks * 16 + 16; ++kt) {
        // ---- S = Q . K^T for this wave's [16q x 32key] quadrant ----------
        floatx4 S0 = (floatx4){0.f, 0.f, 0.f, 0.f};
        floatx4 S1 = (floatx4){0.f, 0.f, 0.f, 0.f};
        const int k16a = kt * 4 + kh * 2;
#pragma unroll
        for (int fc = 0; fc < 8; ++fc) {
            const size_t offa = ((size_t)(b * 8 + fc) * 128 + k16a) * 512 + lane * 8;
            short8 bh0 = *(const short8*)&kfh[offa];
            short8 bl0 = *(const short8*)&kfl[offa];
            short8 bh1 = *(const short8*)&kfh[offa + 512];
            short8 bl1 = *(const short8*)&kfl[offa + 512];
            S0 = __builtin_amdgcn_mfma_f32_16x16x32_bf16(qh[fc], bh0, S0, 0, 0, 0);
            S1 = __builtin_amdgcn_mfma_f32_16x16x32_bf16(qh[fc], bh1, S1, 0, 0, 0);
            S0 = __builtin_amdgcn_mfma_f32_16x16x32_bf16(qh[fc], bl0, S0, 0, 0, 0);
            S1 = __builtin_amdgcn_mfma_f32_16x16x32_bf16(qh[fc], bl1, S1, 0, 0, 0);
            S0 = __builtin_amdgcn_mfma_f32_16x16x32_bf16(ql[fc], bh0, S0, 0, 0, 0);
            S1 = __builtin_amdgcn_mfma_f32_16x16x32_bf16(ql[fc], bh1, S1, 0, 0, 0);
        }

        // ---- exp (max-free, scores bounded ~30) + write P to LDS ---------
#pragma unroll
        for (int r = 0; r < 4; ++r) {
            const float e0 = __expf(S0[r]);
            const float e1 = __expf(S1[r]);
            lsum[r] += e0 + e1;
            P_lds[qs * 16 + quad * 4 + r][kh * 32 + l15]      = e0;
            P_lds[qs * 16 + quad * 4 + r][kh * 32 + 16 + l15] = e1;
        }
        __syncthreads();

        // ---- read P in A-layout (b128), convert to bf16 hi/lo ------------
        short8 ph[2], pl[2];
#pragma unroll
        for (int kc = 0; kc < 2; ++kc) {
            float pv[8];
            *(float4*)&pv[0] = *(const float4*)&P_lds[qs * 16 + l15][kc * 32 + quad * 8];
            *(float4*)&pv[4] = *(const float4*)&P_lds[qs * 16 + l15][kc * 32 + quad * 8 + 4];
#pragma unroll
            for (int j = 0; j < 8; ++j) {
                const short hh = f2bf(pv[j]);
                ph[kc][j] = hh;
                pl[kc][j] = f2bf(pv[j] - bf2f(hh));
            }
        }
        __syncthreads();   // readers done -> next kt may overwrite

        // ---- O += P . feat  (wave's 128-f half) --------------------------
#pragma unroll
        for (int ft = 0; ft < 8; ++ft) {
            const int ftile = kh * 8 + ft;
            const size_t offf = (((size_t)b * 16 + ftile) * 64 + kt * 2) * 512 + lane * 8;
#pragma unroll
            for (int kc = 0; kc < 2; ++kc) {
                short8 bh = *(const short8*)&ffh[offf + kc * 512];
                short8 bl = *(const short8*)&ffl[offf + kc * 512];
                O[ft] = __builtin_amdgcn_mfma_f32_16x16x32_bf16(ph[kc], bh, O[ft], 0, 0, 0);
                O[ft] = __builtin_amdgcn_mfma_f32_16x16x32_bf16(ph[kc], bl, O[ft], 0, 0, 0);
                O[ft] = __builtin_amdgcn_mfma_f32_16x16x32_bf16(pl[kc], bh, O[ft], 0, 0, 0);
            }
        }
    }

    // ---- combine l across col-lanes, then across kh halves ---------------
#pragma unroll
    for (int r = 0; r < 4; ++r) {
        lsum[r] += __shfl_xor(lsum[r], 1, 64);
        lsum[r] += __shfl_xor(lsum[r], 2, 64);
        lsum[r] += __shfl_xor(lsum[r], 4, 64);
        lsum[r] += __shfl_xor(lsum[r], 8, 64);
    }
    if (l15 == 0) {
#pragma unroll
        for (int r = 0; r < 4; ++r)
            l_lds[kh][qs * 16 + quad * 4 + r] = lsum[r];
    }
    __syncthreads();

    float* __restrict__ opart = ks ? o1 : o0;
    const size_t row0 = (size_t)b * T_ + qt * 64;

    if (tid < 64)
        lpart[(size_t)ks * M_TOT + row0 + tid] = l_lds[0][tid] + l_lds[1][tid];

#pragma unroll
    for (int r = 0; r < 4; ++r) {
        const int qr = qs * 16 + quad * 4 + r;
#pragma unroll
        for (int ft = 0; ft < 8; ++ft)
            opart[(row0 + qr) * F_ + kh * 128 + ft * 16 + l15] = O[ft][r];
    }
}

// ---------------------------------------------------------------------------
// Kernel 7: combine split-K partials: out = (O0 + O1) / (l0 + l1)
// ---------------------------------------------------------------------------
__global__ __launch_bounds__(256) void combine_kernel(
    float* __restrict__ out_feat, const float* __restrict__ o1,
    const float* __restrict__ lpart)
{
    const size_t gid = (size_t)blockIdx.x * 256 + threadIdx.x;  // float4 index
    const size_t row = gid >> 6;
    const float inv = 1.0f / (lpart[row] + lpart[M_TOT + row]);
    float4 a = ((const float4*)out_feat)[gid];
    float4 bx = ((const float4*)o1)[gid];
    a.x = (a.x + bx.x) * inv; a.y = (a.y + bx.y) * inv;
    a.z = (a.z + bx.z) * inv; a.w = (a.w + bx.w) * inv;
    ((float4*)out_feat)[gid] = a;
}

extern "C" void kernel_launch(void* const* d_in, const int* in_sizes, int n_in,
                              void* d_out, int out_size, void* d_ws, size_t ws_size,
                              hipStream_t stream)
{
    const float* feat = (const float*)d_in[0];
    // d_in[1] = hlens (unused: reference overwrites peaks -> hlens_new = T)
    const float* Wq = (const float*)d_in[2];
    const float* bq = (const float*)d_in[3];
    const float* Wk = (const float*)d_in[4];
    const float* bk = (const float*)d_in[5];

    float* out_feat  = (float*)d_out;                       // [8,2048,256]
    float* out_hlens = out_feat + (size_t)M_TOT * F_;       // [8]
    float* out_score = out_hlens + B_;                      // [8,2048]

    // workspace layout (~80.6 MB). q/kpart are DEAD after score/pack kernels
    // and are reused as split-K partial buffers by attn_mfma/combine.
    float* q     = (float*)d_ws;                            // 16 MB
    float* k     = q + (size_t)M_TOT * F_;                  // 16 MB
    float* kpart = k + (size_t)M_TOT * F_;                  // 256 KB
    short* qfh = (short*)(kpart + B_ * 32 * F_);            // 8 MB each:
    short* qfl = qfh + (size_t)M_TOT * F_;
    short* kfh = qfl + (size_t)M_TOT * F_;
    short* kfl = kfh + (size_t)M_TOT * F_;
    short* ffh = kfl + (size_t)M_TOT * F_;
    short* ffl = ffh + (size_t)M_TOT * F_;
    float* o1    = q;       // alias: O partial for key-split 1 (16 MB)
    float* lpart = kpart;   // alias: l partials [2][16384] (128 KB)

    dim3 pgrid(M_TOT / 64, 8);
    qk_proj<<<pgrid, 256, 0, stream>>>(feat, Wq, bq, Wk, bk, q, k);

    dim3 kgrid(32, B_);
    kpart_kernel<<<kgrid, 256, 0, stream>>>(k, kpart, out_hlens);

    score_kernel<<<256, 256, 0, stream>>>(q, kpart, out_score);

    pack_qk<<<2048, 256, 0, stream>>>(q, k, qfh, qfl, kfh, kfl);

    dim3 fgrid(64, B_);
    pack_feat<<<fgrid, 256, 0, stream>>>(feat, ffh, ffl);

    attn_mfma<<<512, 512, 0, stream>>>(qfh, qfl, kfh, kfl, ffh, ffl,
                                       out_feat, o1, lpart);

    combine_kernel<<<M_TOT * F_ / 4 / 256, 256, 0, stream>>>(out_feat, o1, lpart);
}

// Round 7
// 320.353 us; speedup vs baseline: 1.2032x; 1.2032x over previous
//
#include <hip/hip_runtime.h>
#include <math.h>

#define B_ 8
#define T_ 2048
#define F_ 256
#define M_TOT (B_ * T_)   // 16384

typedef __attribute__((ext_vector_type(8))) short short8;
typedef __attribute__((ext_vector_type(4))) float floatx4;

// bf16 round-to-nearest-even helpers (finite inputs only)
__device__ __forceinline__ short f2bf(float x) {
    unsigned u = __float_as_uint(x);
    u += 0x7FFF + ((u >> 16) & 1);
    return (short)(u >> 16);
}
__device__ __forceinline__ float bf2f(short s) {
    return __uint_as_float(((unsigned)(unsigned short)s) << 16);
}

// ---------------------------------------------------------------------------
// Kernel 1: fused q/k projection  out = feat @ W^T + b  (fp32)
// ---------------------------------------------------------------------------
__global__ __launch_bounds__(256) void qk_proj(
    const float* __restrict__ feat,
    const float* __restrict__ Wq, const float* __restrict__ bq,
    const float* __restrict__ Wk, const float* __restrict__ bk,
    float* __restrict__ q, float* __restrict__ k)
{
    __shared__ float As[16][64];
    __shared__ float Bs[16][64];

    const int tid = threadIdx.x;
    const int bm  = blockIdx.x;
    const int bn  = blockIdx.y;
    const bool isK = bn >= 4;
    const float* __restrict__ W    = isK ? Wk : Wq;
    const float* __restrict__ bias = isK ? bk : bq;
    float* __restrict__ out        = isK ? k : q;
    const int n0 = (bn & 3) * 64;
    const int m0 = bm * 64;

    const int tx = tid & 15;
    const int ty = tid >> 4;
    const int lr = tid >> 2;
    const int lc = (tid & 3) * 4;

    float acc[4][4] = {};

    for (int k0 = 0; k0 < 256; k0 += 16) {
        float4 a4 = *(const float4*)&feat[(size_t)(m0 + lr) * F_ + k0 + lc];
        float4 b4 = *(const float4*)&W   [(size_t)(n0 + lr) * F_ + k0 + lc];
        __syncthreads();
        As[lc + 0][lr] = a4.x; As[lc + 1][lr] = a4.y;
        As[lc + 2][lr] = a4.z; As[lc + 3][lr] = a4.w;
        Bs[lc + 0][lr] = b4.x; Bs[lc + 1][lr] = b4.y;
        Bs[lc + 2][lr] = b4.z; Bs[lc + 3][lr] = b4.w;
        __syncthreads();
#pragma unroll
        for (int kk = 0; kk < 16; ++kk) {
            float av[4], bv[4];
            *(float4*)av = *(const float4*)&As[kk][ty * 4];
            *(float4*)bv = *(const float4*)&Bs[kk][tx * 4];
#pragma unroll
            for (int i = 0; i < 4; ++i)
#pragma unroll
                for (int j = 0; j < 4; ++j)
                    acc[i][j] += av[i] * bv[j];
        }
    }

    const float4 bias4 = *(const float4*)&bias[n0 + tx * 4];
    const float bb[4] = {bias4.x, bias4.y, bias4.z, bias4.w};
#pragma unroll
    for (int i = 0; i < 4; ++i) {
        const int m = m0 + ty * 4 + i;
        float4 o;
        o.x = acc[i][0] + bb[0];
        o.y = acc[i][1] + bb[1];
        o.z = acc[i][2] + bb[2];
        o.w = acc[i][3] + bb[3];
        *(float4*)&out[(size_t)m * F_ + n0 + tx * 4] = o;
    }
}

// ---------------------------------------------------------------------------
// Kernel 2: per-batch partial column sums of k (score = q . mean(k)) + hlens
// ---------------------------------------------------------------------------
__global__ __launch_bounds__(256) void kpart_kernel(
    const float* __restrict__ k, float* __restrict__ kpart,
    float* __restrict__ out_hlens)
{
    const int c = blockIdx.x;
    const int b = blockIdx.y;
    const int tid = threadIdx.x;
    const float* base = &k[((size_t)b * T_ + c * 64) * F_ + tid];
    float s = 0.f;
#pragma unroll 8
    for (int r = 0; r < 64; ++r) s += base[(size_t)r * F_];
    kpart[((size_t)b * 32 + c) * F_ + tid] = s;
    if (b == 0 && c == 0 && tid < B_) out_hlens[tid] = (float)T_;
}

// ---------------------------------------------------------------------------
// Kernel 3: score[b][t] = q_t . kbar_b
// ---------------------------------------------------------------------------
__global__ __launch_bounds__(256) void score_kernel(
    const float* __restrict__ q, const float* __restrict__ kpart,
    float* __restrict__ out_score)
{
    __shared__ float kbar[256];
    const int tid = threadIdx.x;
    const int b   = blockIdx.x >> 5;
    const int t0s = (blockIdx.x & 31) * 64;

    {
        float s = 0.f;
#pragma unroll 8
        for (int c = 0; c < 32; ++c) s += kpart[((size_t)b * 32 + c) * F_ + tid];
        kbar[tid] = s * (1.0f / (float)T_);
    }
    __syncthreads();

    const int row = t0s + (tid >> 2);
    const int fq  = (tid & 3) * 64;
    const float* qr = &q[((size_t)b * T_ + row) * F_ + fq];
    float s = 0.f;
#pragma unroll
    for (int i = 0; i < 16; ++i) {
        float4 v = *(const float4*)&qr[i * 4];
        s += v.x * kbar[fq + i * 4 + 0] + v.y * kbar[fq + i * 4 + 1]
           + v.z * kbar[fq + i * 4 + 2] + v.w * kbar[fq + i * 4 + 3];
    }
    s += __shfl_xor(s, 1, 64);
    s += __shfl_xor(s, 2, 64);
    if ((tid & 3) == 0) out_score[(size_t)b * T_ + row] = s;
}

// ---------------------------------------------------------------------------
// Kernel 4: pack q (hi+lo) and k (hi only) -> MFMA fragment order bf16.
// S-phase uses split-2: S = (qh+ql).kh, so kl is never needed.
// ---------------------------------------------------------------------------
__global__ __launch_bounds__(256) void pack_qk(
    const float* __restrict__ q, const float* __restrict__ k,
    short* __restrict__ qfh, short* __restrict__ qfl,
    short* __restrict__ kfh)
{
    const int tid  = threadIdx.x;
    const int lane = tid & 63;
    const int t    = blockIdx.x * 4 + (tid >> 6);   // 0..8191
    const int b    = t >> 10;
    const int fc   = (t >> 7) & 7;
    const int r16  = t & 127;

    const size_t srow = (size_t)b * T_ + r16 * 16 + (lane & 15);
    const int    col  = fc * 32 + (lane >> 4) * 8;
    const size_t dst  = (size_t)t * 512 + lane * 8;

    {
        float v[8];
        *(float4*)&v[0] = *(const float4*)&q[srow * F_ + col];
        *(float4*)&v[4] = *(const float4*)&q[srow * F_ + col + 4];
        short8 h, l;
#pragma unroll
        for (int j = 0; j < 8; ++j) {
            short hh = f2bf(v[j]);
            h[j] = hh; l[j] = f2bf(v[j] - bf2f(hh));
        }
        *(short8*)&qfh[dst] = h;
        *(short8*)&qfl[dst] = l;
    }
    {
        float v[8];
        *(float4*)&v[0] = *(const float4*)&k[srow * F_ + col];
        *(float4*)&v[4] = *(const float4*)&k[srow * F_ + col + 4];
        short8 h;
#pragma unroll
        for (int j = 0; j < 8; ++j) h[j] = f2bf(v[j]);
        *(short8*)&kfh[dst] = h;
    }
}

// ---------------------------------------------------------------------------
// Kernel 5: pack feat (hi only) -> B-fragment order for PV.
// PV uses split-2: O = (ph+pl).fh, so fl is never needed.
// ---------------------------------------------------------------------------
__global__ __launch_bounds__(256) void pack_feat(
    const float* __restrict__ feat,
    short* __restrict__ ffh)
{
    __shared__ float lds[32][257];
    const int tid = threadIdx.x;
    const int kc  = blockIdx.x;   // 0..63
    const int b   = blockIdx.y;

#pragma unroll
    for (int i = 0; i < 8; ++i) {
        const int lin = i * 256 + tid;
        const int r = lin >> 6, c4 = (lin & 63) * 4;
        float4 v = *(const float4*)&feat[((size_t)b * T_ + kc * 32 + r) * F_ + c4];
        lds[r][c4 + 0] = v.x; lds[r][c4 + 1] = v.y;
        lds[r][c4 + 2] = v.z; lds[r][c4 + 3] = v.w;
    }
    __syncthreads();

    const int lane = tid & 63, g = tid >> 6;
    const int quad = lane >> 4, l15 = lane & 15;
#pragma unroll
    for (int fi = 0; fi < 4; ++fi) {
        const int ft = g + fi * 4;
        short8 h;
#pragma unroll
        for (int j = 0; j < 8; ++j)
            h[j] = f2bf(lds[quad * 8 + j][ft * 16 + l15]);
        const size_t dst = (((size_t)b * 16 + ft) * 64 + kc) * 512 + lane * 8;
        *(short8*)&ffh[dst] = h;
    }
}

// ---------------------------------------------------------------------------
// Kernel 6: fused flash attention, MFMA bf16, A-side hi/lo split-2, split-K.
// 1D grid of 512 blocks, XCD-pinned (batch = blockIdx.x & 7). Per-XCD hot
// fragment set now ~2 MB (kfh+ffh halves) -> fits the 4 MB L2.
// O-partial/l stores are NONTEMPORAL: streaming writes must not evict L2
// read lines (R4/R5 write-allocate pollution).
// Block: 64 queries, 512 threads = 8 waves: wave = (qs 0..3, kh 0..1).
// ---------------------------------------------------------------------------
__global__ __launch_bounds__(512, 4) void attn_mfma(
    const short* __restrict__ qfh, const short* __restrict__ qfl,
    const short* __restrict__ kfh,
    const short* __restrict__ ffh,
    float* __restrict__ o0, float* __restrict__ o1,
    float* __restrict__ lpart)
{
    __shared__ float P_lds[64][68];   // pad 68: 16B-aligned rows for b128 reads
    __shared__ float l_lds[2][64];

    const int tid  = threadIdx.x;
    const int wave = tid >> 6, lane = tid & 63;
    const int qs   = wave & 3, kh = wave >> 2;
    const int quad = lane >> 4, l15 = lane & 15;

    const int lid  = blockIdx.x;      // 0..511
    const int b    = lid & 7;         // XCD pin: batch -> XCD
    const int qt   = (lid >> 3) & 31; // q-tile within batch
    const int ks   = lid >> 8;        // split-K half
    const int qt16 = qt * 4 + qs;

    // persistent Q fragments (A-operand), hi/lo
    short8 qh[8], ql[8];
#pragma unroll
    for (int fc = 0; fc < 8; ++fc) {
        const size_t off = ((size_t)(b * 8 + fc) * 128 + qt16) * 512 + lane * 8;
        qh[fc] = *(const short8*)&qfh[off];
        ql[fc] = *(const short8*)&qfl[off];
    }

    floatx4 O[8];
#pragma unroll
    for (int i = 0; i < 8; ++i) O[i] = (floatx4){0.f, 0.f, 0.f, 0.f};
    float lsum[4] = {0.f, 0.f, 0.f, 0.f};

    for (int kt = ks * 16; kt < ks * 16 + 16; ++kt) {
        // ---- S = (qh+ql) . kh^T for this wave's [16q x 32key] quadrant ---
        floatx4 S0 = (floatx4){0.f, 0.f, 0.f, 0.f};
        floatx4 S1 = (floatx4){0.f, 0.f, 0.f, 0.f};
        const int k16a = kt * 4 + kh * 2;
#pragma unroll
        for (int fc = 0; fc < 8; ++fc) {
            const size_t offa = ((size_t)(b * 8 + fc) * 128 + k16a) * 512 + lane * 8;
            short8 bh0 = *(const short8*)&kfh[offa];
            short8 bh1 = *(const short8*)&kfh[offa + 512];
            S0 = __builtin_amdgcn_mfma_f32_16x16x32_bf16(qh[fc], bh0, S0, 0, 0, 0);
            S1 = __builtin_amdgcn_mfma_f32_16x16x32_bf16(qh[fc], bh1, S1, 0, 0, 0);
            S0 = __builtin_amdgcn_mfma_f32_16x16x32_bf16(ql[fc], bh0, S0, 0, 0, 0);
            S1 = __builtin_amdgcn_mfma_f32_16x16x32_bf16(ql[fc], bh1, S1, 0, 0, 0);
        }

        // ---- exp (max-free, scores bounded ~30) + write P to LDS ---------
#pragma unroll
        for (int r = 0; r < 4; ++r) {
            const float e0 = __expf(S0[r]);
            const float e1 = __expf(S1[r]);
            lsum[r] += e0 + e1;
            P_lds[qs * 16 + quad * 4 + r][kh * 32 + l15]      = e0;
            P_lds[qs * 16 + quad * 4 + r][kh * 32 + 16 + l15] = e1;
        }
        __syncthreads();

        // ---- read P in A-layout (b128), convert to bf16 hi/lo ------------
        short8 ph[2], pl[2];
#pragma unroll
        for (int kc = 0; kc < 2; ++kc) {
            float pv[8];
            *(float4*)&pv[0] = *(const float4*)&P_lds[qs * 16 + l15][kc * 32 + quad * 8];
            *(float4*)&pv[4] = *(const float4*)&P_lds[qs * 16 + l15][kc * 32 + quad * 8 + 4];
#pragma unroll
            for (int j = 0; j < 8; ++j) {
                const short hh = f2bf(pv[j]);
                ph[kc][j] = hh;
                pl[kc][j] = f2bf(pv[j] - bf2f(hh));
            }
        }
        __syncthreads();   // readers done -> next kt may overwrite

        // ---- O += (ph+pl) . fh  (wave's 128-f half) ----------------------
#pragma unroll
        for (int ft = 0; ft < 8; ++ft) {
            const int ftile = kh * 8 + ft;
            const size_t offf = (((size_t)b * 16 + ftile) * 64 + kt * 2) * 512 + lane * 8;
#pragma unroll
            for (int kc = 0; kc < 2; ++kc) {
                short8 bh = *(const short8*)&ffh[offf + kc * 512];
                O[ft] = __builtin_amdgcn_mfma_f32_16x16x32_bf16(ph[kc], bh, O[ft], 0, 0, 0);
                O[ft] = __builtin_amdgcn_mfma_f32_16x16x32_bf16(pl[kc], bh, O[ft], 0, 0, 0);
            }
        }
    }

    // ---- combine l across col-lanes, then across kh halves ---------------
#pragma unroll
    for (int r = 0; r < 4; ++r) {
        lsum[r] += __shfl_xor(lsum[r], 1, 64);
        lsum[r] += __shfl_xor(lsum[r], 2, 64);
        lsum[r] += __shfl_xor(lsum[r], 4, 64);
        lsum[r] += __shfl_xor(lsum[r], 8, 64);
    }
    if (l15 == 0) {
#pragma unroll
        for (int r = 0; r < 4; ++r)
            l_lds[kh][qs * 16 + quad * 4 + r] = lsum[r];
    }
    __syncthreads();

    float* __restrict__ opart = ks ? o1 : o0;
    const size_t row0 = (size_t)b * T_ + qt * 64;

    if (tid < 64)
        __builtin_nontemporal_store(l_lds[0][tid] + l_lds[1][tid],
                                    &lpart[(size_t)ks * M_TOT + row0 + tid]);

#pragma unroll
    for (int r = 0; r < 4; ++r) {
        const int qr = qs * 16 + quad * 4 + r;
#pragma unroll
        for (int ft = 0; ft < 8; ++ft)
            __builtin_nontemporal_store(
                O[ft][r], &opart[(row0 + qr) * F_ + kh * 128 + ft * 16 + l15]);
    }
}

// ---------------------------------------------------------------------------
// Kernel 7: combine split-K partials: out = (O0 + O1) / (l0 + l1)
// Uses ext_vector_type for nontemporal builtins (HIP float4 is rejected).
// ---------------------------------------------------------------------------
__global__ __launch_bounds__(256) void combine_kernel(
    float* __restrict__ out_feat, const float* __restrict__ o1,
    const float* __restrict__ lpart)
{
    const size_t gid = (size_t)blockIdx.x * 256 + threadIdx.x;  // float4 index
    const size_t row = gid >> 6;
    const float inv = 1.0f / (lpart[row] + lpart[M_TOT + row]);
    floatx4 a  = __builtin_nontemporal_load(&((const floatx4*)out_feat)[gid]);
    floatx4 bx = __builtin_nontemporal_load(&((const floatx4*)o1)[gid]);
    a = (a + bx) * inv;
    __builtin_nontemporal_store(a, &((floatx4*)out_feat)[gid]);
}

extern "C" void kernel_launch(void* const* d_in, const int* in_sizes, int n_in,
                              void* d_out, int out_size, void* d_ws, size_t ws_size,
                              hipStream_t stream)
{
    const float* feat = (const float*)d_in[0];
    // d_in[1] = hlens (unused: reference overwrites peaks -> hlens_new = T)
    const float* Wq = (const float*)d_in[2];
    const float* bq = (const float*)d_in[3];
    const float* Wk = (const float*)d_in[4];
    const float* bk = (const float*)d_in[5];

    float* out_feat  = (float*)d_out;                       // [8,2048,256]
    float* out_hlens = out_feat + (size_t)M_TOT * F_;       // [8]
    float* out_score = out_hlens + B_;                      // [8,2048]

    // workspace (~64.4 MB). q/kpart are DEAD after score/pack and are reused
    // as split-K partial buffers by attn_mfma/combine.
    float* q     = (float*)d_ws;                            // 16 MB
    float* k     = q + (size_t)M_TOT * F_;                  // 16 MB
    float* kpart = k + (size_t)M_TOT * F_;                  // 256 KB
    short* qfh = (short*)(kpart + B_ * 32 * F_);            // 8 MB each:
    short* qfl = qfh + (size_t)M_TOT * F_;
    short* kfh = qfl + (size_t)M_TOT * F_;
    short* ffh = kfh + (size_t)M_TOT * F_;
    float* o1    = q;       // alias: O partial for key-split 1 (16 MB)
    float* lpart = kpart;   // alias: l partials [2][16384] (128 KB)

    dim3 pgrid(M_TOT / 64, 8);
    qk_proj<<<pgrid, 256, 0, stream>>>(feat, Wq, bq, Wk, bk, q, k);

    dim3 kgrid(32, B_);
    kpart_kernel<<<kgrid, 256, 0, stream>>>(k, kpart, out_hlens);

    score_kernel<<<256, 256, 0, stream>>>(q, kpart, out_score);

    pack_qk<<<2048, 256, 0, stream>>>(q, k, qfh, qfl, kfh);

    dim3 fgrid(64, B_);
    pack_feat<<<fgrid, 256, 0, stream>>>(feat, ffh);

    attn_mfma<<<512, 512, 0, stream>>>(qfh, qfl, kfh, ffh,
                                       out_feat, o1, lpart);

    combine_kernel<<<M_TOT * F_ / 4 / 256, 256, 0, stream>>>(out_feat, o1, lpart);
}

// Round 8
// 245.630 us; speedup vs baseline: 1.5692x; 1.3042x over previous
//
#include <hip/hip_runtime.h>
#include <math.h>

#define B_ 8
#define T_ 2048
#define F_ 256
#define M_TOT (B_ * T_)   // 16384

typedef __attribute__((ext_vector_type(8))) short short8;
typedef __attribute__((ext_vector_type(4))) float floatx4;

// bf16 round-to-nearest-even helpers (finite inputs only)
__device__ __forceinline__ short f2bf(float x) {
    unsigned u = __float_as_uint(x);
    u += 0x7FFF + ((u >> 16) & 1);
    return (short)(u >> 16);
}
__device__ __forceinline__ float bf2f(short s) {
    return __uint_as_float(((unsigned)(unsigned short)s) << 16);
}

// async global -> LDS copy, 16 B per lane (gfx950 global_load_lds_dwordx4)
__device__ __forceinline__ void cp_g2l_16(const void* g, void* l) {
    __builtin_amdgcn_global_load_lds(
        (const __attribute__((address_space(1))) void*)g,
        (__attribute__((address_space(3))) void*)l, 16, 0, 0);
}

// ---------------------------------------------------------------------------
// Kernel 1: fused q/k projection  out = feat @ W^T + b  (fp32)
// ---------------------------------------------------------------------------
__global__ __launch_bounds__(256) void qk_proj(
    const float* __restrict__ feat,
    const float* __restrict__ Wq, const float* __restrict__ bq,
    const float* __restrict__ Wk, const float* __restrict__ bk,
    float* __restrict__ q, float* __restrict__ k)
{
    __shared__ float As[16][64];
    __shared__ float Bs[16][64];

    const int tid = threadIdx.x;
    const int bm  = blockIdx.x;
    const int bn  = blockIdx.y;
    const bool isK = bn >= 4;
    const float* __restrict__ W    = isK ? Wk : Wq;
    const float* __restrict__ bias = isK ? bk : bq;
    float* __restrict__ out        = isK ? k : q;
    const int n0 = (bn & 3) * 64;
    const int m0 = bm * 64;

    const int tx = tid & 15;
    const int ty = tid >> 4;
    const int lr = tid >> 2;
    const int lc = (tid & 3) * 4;

    float acc[4][4] = {};

    for (int k0 = 0; k0 < 256; k0 += 16) {
        float4 a4 = *(const float4*)&feat[(size_t)(m0 + lr) * F_ + k0 + lc];
        float4 b4 = *(const float4*)&W   [(size_t)(n0 + lr) * F_ + k0 + lc];
        __syncthreads();
        As[lc + 0][lr] = a4.x; As[lc + 1][lr] = a4.y;
        As[lc + 2][lr] = a4.z; As[lc + 3][lr] = a4.w;
        Bs[lc + 0][lr] = b4.x; Bs[lc + 1][lr] = b4.y;
        Bs[lc + 2][lr] = b4.z; Bs[lc + 3][lr] = b4.w;
        __syncthreads();
#pragma unroll
        for (int kk = 0; kk < 16; ++kk) {
            float av[4], bv[4];
            *(float4*)av = *(const float4*)&As[kk][ty * 4];
            *(float4*)bv = *(const float4*)&Bs[kk][tx * 4];
#pragma unroll
            for (int i = 0; i < 4; ++i)
#pragma unroll
                for (int j = 0; j < 4; ++j)
                    acc[i][j] += av[i] * bv[j];
        }
    }

    const float4 bias4 = *(const float4*)&bias[n0 + tx * 4];
    const float bb[4] = {bias4.x, bias4.y, bias4.z, bias4.w};
#pragma unroll
    for (int i = 0; i < 4; ++i) {
        const int m = m0 + ty * 4 + i;
        float4 o;
        o.x = acc[i][0] + bb[0];
        o.y = acc[i][1] + bb[1];
        o.z = acc[i][2] + bb[2];
        o.w = acc[i][3] + bb[3];
        *(float4*)&out[(size_t)m * F_ + n0 + tx * 4] = o;
    }
}

// ---------------------------------------------------------------------------
// Kernel 2: per-batch partial column sums of k (score = q . mean(k)) + hlens
// ---------------------------------------------------------------------------
__global__ __launch_bounds__(256) void kpart_kernel(
    const float* __restrict__ k, float* __restrict__ kpart,
    float* __restrict__ out_hlens)
{
    const int c = blockIdx.x;
    const int b = blockIdx.y;
    const int tid = threadIdx.x;
    const float* base = &k[((size_t)b * T_ + c * 64) * F_ + tid];
    float s = 0.f;
#pragma unroll 8
    for (int r = 0; r < 64; ++r) s += base[(size_t)r * F_];
    kpart[((size_t)b * 32 + c) * F_ + tid] = s;
    if (b == 0 && c == 0 && tid < B_) out_hlens[tid] = (float)T_;
}

// ---------------------------------------------------------------------------
// Kernel 3: score[b][t] = q_t . kbar_b
// ---------------------------------------------------------------------------
__global__ __launch_bounds__(256) void score_kernel(
    const float* __restrict__ q, const float* __restrict__ kpart,
    float* __restrict__ out_score)
{
    __shared__ float kbar[256];
    const int tid = threadIdx.x;
    const int b   = blockIdx.x >> 5;
    const int t0s = (blockIdx.x & 31) * 64;

    {
        float s = 0.f;
#pragma unroll 8
        for (int c = 0; c < 32; ++c) s += kpart[((size_t)b * 32 + c) * F_ + tid];
        kbar[tid] = s * (1.0f / (float)T_);
    }
    __syncthreads();

    const int row = t0s + (tid >> 2);
    const int fq  = (tid & 3) * 64;
    const float* qr = &q[((size_t)b * T_ + row) * F_ + fq];
    float s = 0.f;
#pragma unroll
    for (int i = 0; i < 16; ++i) {
        float4 v = *(const float4*)&qr[i * 4];
        s += v.x * kbar[fq + i * 4 + 0] + v.y * kbar[fq + i * 4 + 1]
           + v.z * kbar[fq + i * 4 + 2] + v.w * kbar[fq + i * 4 + 3];
    }
    s += __shfl_xor(s, 1, 64);
    s += __shfl_xor(s, 2, 64);
    if ((tid & 3) == 0) out_score[(size_t)b * T_ + row] = s;
}

// ---------------------------------------------------------------------------
// Kernel 4: pack q (hi+lo, fragment array) and k (hi only, into staged
// per-(b,kt32) contiguous 32 KB blocks consumed by attn DMA).
// Staged block layout (shorts): kf tile (fc,slot) at (fc*2+slot)*512,
// ff tile ft at 8192 + ft*512.
// ---------------------------------------------------------------------------
__global__ __launch_bounds__(256) void pack_qk(
    const float* __restrict__ q, const float* __restrict__ k,
    short* __restrict__ qfh, short* __restrict__ qfl,
    short* __restrict__ stg)
{
    const int tid  = threadIdx.x;
    const int lane = tid & 63;
    const int t    = blockIdx.x * 4 + (tid >> 6);   // 0..8191
    const int b    = t >> 10;
    const int fc   = (t >> 7) & 7;
    const int r16  = t & 127;

    const size_t srow = (size_t)b * T_ + r16 * 16 + (lane & 15);
    const int    col  = fc * 32 + (lane >> 4) * 8;

    {
        const size_t dst = (size_t)t * 512 + lane * 8;
        float v[8];
        *(float4*)&v[0] = *(const float4*)&q[srow * F_ + col];
        *(float4*)&v[4] = *(const float4*)&q[srow * F_ + col + 4];
        short8 h, l;
#pragma unroll
        for (int j = 0; j < 8; ++j) {
            short hh = f2bf(v[j]);
            h[j] = hh; l[j] = f2bf(v[j] - bf2f(hh));
        }
        *(short8*)&qfh[dst] = h;
        *(short8*)&qfl[dst] = l;
    }
    {
        const int kt   = r16 >> 1;      // 32-key tile index 0..63
        const int slot = r16 & 1;       // 16-key half within tile
        const size_t dst = ((size_t)(b * 64 + kt)) * 16384
                         + (fc * 2 + slot) * 512 + lane * 8;
        float v[8];
        *(float4*)&v[0] = *(const float4*)&k[srow * F_ + col];
        *(float4*)&v[4] = *(const float4*)&k[srow * F_ + col + 4];
        short8 h;
#pragma unroll
        for (int j = 0; j < 8; ++j) h[j] = f2bf(v[j]);
        *(short8*)&stg[dst] = h;
    }
}

// ---------------------------------------------------------------------------
// Kernel 5: pack feat (hi only) -> ff part of staged blocks.
// ---------------------------------------------------------------------------
__global__ __launch_bounds__(256) void pack_feat(
    const float* __restrict__ feat,
    short* __restrict__ stg)
{
    __shared__ float lds[32][257];
    const int tid = threadIdx.x;
    const int kc  = blockIdx.x;   // 0..63  == kt32
    const int b   = blockIdx.y;

#pragma unroll
    for (int i = 0; i < 8; ++i) {
        const int lin = i * 256 + tid;
        const int r = lin >> 6, c4 = (lin & 63) * 4;
        float4 v = *(const float4*)&feat[((size_t)b * T_ + kc * 32 + r) * F_ + c4];
        lds[r][c4 + 0] = v.x; lds[r][c4 + 1] = v.y;
        lds[r][c4 + 2] = v.z; lds[r][c4 + 3] = v.w;
    }
    __syncthreads();

    const int lane = tid & 63, g = tid >> 6;
    const int quad = lane >> 4, l15 = lane & 15;
#pragma unroll
    for (int fi = 0; fi < 4; ++fi) {
        const int ft = g + fi * 4;
        short8 h;
#pragma unroll
        for (int j = 0; j < 8; ++j)
            h[j] = f2bf(lds[quad * 8 + j][ft * 16 + l15]);
        const size_t dst = ((size_t)(b * 64 + kc)) * 16384
                         + 8192 + ft * 512 + lane * 8;
        *(short8*)&stg[dst] = h;
    }
}

// ---------------------------------------------------------------------------
// Kernel 6: fused flash attention. K-tiles of 32 keys; per kt the block DMAs
// one contiguous 32 KB staged block (kf 16K + ff 16K) into LDS via
// global_load_lds (double-buffered, prefetch issued mid-iteration so it
// overlaps the PV phase). Waves read operands with ds_read_b128 — no
// per-wave L2 gathers, no 4x qs-redundant loads.
// 1D grid 512 blocks, XCD-pinned (b = lid & 7). Split-K over key halves.
// Block: 64 queries, 512 threads = 8 waves: wave = (qs 0..3, kh 0..1).
// LDS: 2*32768 + 64*33*4 + 512 = 74.5 KB -> 2 blocks/CU.
// ---------------------------------------------------------------------------
__global__ __launch_bounds__(512, 4) void attn_mfma(
    const short* __restrict__ qfh, const short* __restrict__ qfl,
    const short* __restrict__ stg,
    float* __restrict__ o0, float* __restrict__ o1,
    float* __restrict__ lpart)
{
    __shared__ short kbuf[2][16384];   // staged kt block: kf @0, ff @8192
    __shared__ float P_lds[64 * 33];   // [q][key], pad 33: <=2-way banks
    __shared__ float l_lds[2][64];

    const int tid  = threadIdx.x;
    const int wave = tid >> 6, lane = tid & 63;
    const int qs   = wave & 3, kh = wave >> 2;
    const int quad = lane >> 4, l15 = lane & 15;

    const int lid  = blockIdx.x;      // 0..511
    const int b    = lid & 7;         // XCD pin: batch -> XCD
    const int qt   = (lid >> 3) & 31; // q-tile within batch
    const int ks   = lid >> 8;        // split-K half
    const int qt16 = qt * 4 + qs;

    // persistent Q fragments (A-operand), hi/lo
    short8 qh[8], ql[8];
#pragma unroll
    for (int fc = 0; fc < 8; ++fc) {
        const size_t off = ((size_t)(b * 8 + fc) * 128 + qt16) * 512 + lane * 8;
        qh[fc] = *(const short8*)&qfh[off];
        ql[fc] = *(const short8*)&qfl[off];
    }

    floatx4 O[8];
#pragma unroll
    for (int i = 0; i < 8; ++i) O[i] = (floatx4){0.f, 0.f, 0.f, 0.f};
    float lsum[4] = {0.f, 0.f, 0.f, 0.f};

    const short* sbase = &stg[(size_t)b * 64 * 16384];
    const int kbeg = ks * 32, kend = kbeg + 32;

    // prologue DMA: kt = kbeg into buffer 0 (4 x 16 B per thread = 32 KB)
    {
        const short* src = sbase + (size_t)kbeg * 16384 + tid * 8;
        short* dst = &kbuf[0][tid * 8];
#pragma unroll
        for (int i = 0; i < 4; ++i)
            cp_g2l_16(src + i * 4096, dst + i * 4096);
    }

    int cur = 0;
    for (int kt = kbeg; kt < kend; ++kt, cur ^= 1) {
        __syncthreads();   // drains DMA for kbuf[cur]; P_lds readers done

        // ---- S = (qh+ql) . kh^T, wave's [16q x 16key] quadrant -----------
        floatx4 Sa = (floatx4){0.f, 0.f, 0.f, 0.f};
        floatx4 Sb = (floatx4){0.f, 0.f, 0.f, 0.f};
#pragma unroll
        for (int fc = 0; fc < 8; ++fc) {
            short8 bh = *(const short8*)&kbuf[cur][(fc * 2 + kh) * 512 + lane * 8];
            Sa = __builtin_amdgcn_mfma_f32_16x16x32_bf16(qh[fc], bh, Sa, 0, 0, 0);
            Sb = __builtin_amdgcn_mfma_f32_16x16x32_bf16(ql[fc], bh, Sb, 0, 0, 0);
        }

        // ---- exp (max-free, scores bounded ~30) + write P to LDS ---------
#pragma unroll
        for (int r = 0; r < 4; ++r) {
            const float e = __expf(Sa[r] + Sb[r]);
            lsum[r] += e;
            P_lds[(qs * 16 + quad * 4 + r) * 33 + kh * 16 + l15] = e;
        }
        __syncthreads();

        // ---- read P in A-layout, convert to bf16 hi/lo -------------------
        short8 ph, pl;
#pragma unroll
        for (int j = 0; j < 8; ++j) {
            const float p = P_lds[(qs * 16 + l15) * 33 + quad * 8 + j];
            const short hh = f2bf(p);
            ph[j] = hh;
            pl[j] = f2bf(p - bf2f(hh));
        }

        // ---- prefetch next kt into the other buffer (overlaps PV) --------
        if (kt + 1 < kend) {
            const short* src = sbase + (size_t)(kt + 1) * 16384 + tid * 8;
            short* dst = &kbuf[cur ^ 1][tid * 8];
#pragma unroll
            for (int i = 0; i < 4; ++i)
                cp_g2l_16(src + i * 4096, dst + i * 4096);
        }

        // ---- O += (ph+pl) . fh  (wave's 128-f half) ----------------------
#pragma unroll
        for (int ft = 0; ft < 8; ++ft) {
            short8 fh = *(const short8*)&kbuf[cur][8192 + (kh * 8 + ft) * 512 + lane * 8];
            O[ft] = __builtin_amdgcn_mfma_f32_16x16x32_bf16(ph, fh, O[ft], 0, 0, 0);
            O[ft] = __builtin_amdgcn_mfma_f32_16x16x32_bf16(pl, fh, O[ft], 0, 0, 0);
        }
    }

    // ---- combine l across the 16 key-cols, then across kh halves ---------
#pragma unroll
    for (int r = 0; r < 4; ++r) {
        lsum[r] += __shfl_xor(lsum[r], 1, 64);
        lsum[r] += __shfl_xor(lsum[r], 2, 64);
        lsum[r] += __shfl_xor(lsum[r], 4, 64);
        lsum[r] += __shfl_xor(lsum[r], 8, 64);
    }
    if (l15 == 0) {
#pragma unroll
        for (int r = 0; r < 4; ++r)
            l_lds[kh][qs * 16 + quad * 4 + r] = lsum[r];
    }
    __syncthreads();

    float* __restrict__ opart = ks ? o1 : o0;
    const size_t row0 = (size_t)b * T_ + qt * 64;

    if (tid < 64)
        __builtin_nontemporal_store(l_lds[0][tid] + l_lds[1][tid],
                                    &lpart[(size_t)ks * M_TOT + row0 + tid]);

#pragma unroll
    for (int r = 0; r < 4; ++r) {
        const int qr = qs * 16 + quad * 4 + r;
#pragma unroll
        for (int ft = 0; ft < 8; ++ft)
            __builtin_nontemporal_store(
                O[ft][r], &opart[(row0 + qr) * F_ + kh * 128 + ft * 16 + l15]);
    }
}

// ---------------------------------------------------------------------------
// Kernel 7: combine split-K partials: out = (O0 + O1) / (l0 + l1)
// ---------------------------------------------------------------------------
__global__ __launch_bounds__(256) void combine_kernel(
    float* __restrict__ out_feat, const float* __restrict__ o1,
    const float* __restrict__ lpart)
{
    const size_t gid = (size_t)blockIdx.x * 256 + threadIdx.x;  // float4 index
    const size_t row = gid >> 6;
    const float inv = 1.0f / (lpart[row] + lpart[M_TOT + row]);
    floatx4 a  = __builtin_nontemporal_load(&((const floatx4*)out_feat)[gid]);
    floatx4 bx = __builtin_nontemporal_load(&((const floatx4*)o1)[gid]);
    a = (a + bx) * inv;
    __builtin_nontemporal_store(a, &((floatx4*)out_feat)[gid]);
}

extern "C" void kernel_launch(void* const* d_in, const int* in_sizes, int n_in,
                              void* d_out, int out_size, void* d_ws, size_t ws_size,
                              hipStream_t stream)
{
    const float* feat = (const float*)d_in[0];
    // d_in[1] = hlens (unused: reference overwrites peaks -> hlens_new = T)
    const float* Wq = (const float*)d_in[2];
    const float* bq = (const float*)d_in[3];
    const float* Wk = (const float*)d_in[4];
    const float* bk = (const float*)d_in[5];

    float* out_feat  = (float*)d_out;                       // [8,2048,256]
    float* out_hlens = out_feat + (size_t)M_TOT * F_;       // [8]
    float* out_score = out_hlens + B_;                      // [8,2048]

    // workspace (~64.4 MB). q/kpart are DEAD after score/pack and are reused
    // as split-K partial buffers by attn_mfma/combine.
    float* q     = (float*)d_ws;                            // 16 MB
    float* k     = q + (size_t)M_TOT * F_;                  // 16 MB
    float* kpart = k + (size_t)M_TOT * F_;                  // 256 KB
    short* qfh = (short*)(kpart + B_ * 32 * F_);            // 8 MB
    short* qfl = qfh + (size_t)M_TOT * F_;                  // 8 MB
    short* stg = qfl + (size_t)M_TOT * F_;                  // 16 MB staged k+f
    float* o1    = q;       // alias: O partial for key-split 1 (16 MB)
    float* lpart = kpart;   // alias: l partials [2][16384] (128 KB)

    dim3 pgrid(M_TOT / 64, 8);
    qk_proj<<<pgrid, 256, 0, stream>>>(feat, Wq, bq, Wk, bk, q, k);

    dim3 kgrid(32, B_);
    kpart_kernel<<<kgrid, 256, 0, stream>>>(k, kpart, out_hlens);

    score_kernel<<<256, 256, 0, stream>>>(q, kpart, out_score);

    pack_qk<<<2048, 256, 0, stream>>>(q, k, qfh, qfl, stg);

    dim3 fgrid(64, B_);
    pack_feat<<<fgrid, 256, 0, stream>>>(feat, stg);

    attn_mfma<<<512, 512, 0, stream>>>(qfh, qfl, stg,
                                       out_feat, o1, lpart);

    combine_kernel<<<M_TOT * F_ / 4 / 256, 256, 0, stream>>>(out_feat, o1, lpart);
}

// Round 9
// 220.811 us; speedup vs baseline: 1.7456x; 1.1124x over previous
//
#include <hip/hip_runtime.h>
#include <math.h>

#define B_ 8
#define T_ 2048
#define F_ 256
#define M_TOT (B_ * T_)   // 16384

typedef __attribute__((ext_vector_type(8))) short short8;
typedef __attribute__((ext_vector_type(4))) float floatx4;

// bf16 round-to-nearest-even helpers (finite inputs only)
__device__ __forceinline__ short f2bf(float x) {
    unsigned u = __float_as_uint(x);
    u += 0x7FFF + ((u >> 16) & 1);
    return (short)(u >> 16);
}
__device__ __forceinline__ float bf2f(short s) {
    return __uint_as_float(((unsigned)(unsigned short)s) << 16);
}

// async global -> LDS copy, 16 B per lane (gfx950 global_load_lds_dwordx4)
__device__ __forceinline__ void cp_g2l_16(const void* g, void* l) {
    __builtin_amdgcn_global_load_lds(
        (const __attribute__((address_space(1))) void*)g,
        (__attribute__((address_space(3))) void*)l, 16, 0, 0);
}

// ---------------------------------------------------------------------------
// Kernel 1: one pass over feat producing
//  (a) A-fragments hi/lo for the projection GEMM (featAh/featAl),
//  (b) PV B-fragments (hi) into the staged attn blocks (stg + 8192),
//  (c) per-(b,32-row-chunk) column sums (featpart, for kbar).
// grid (64, 8), 256 threads.
// ---------------------------------------------------------------------------
__global__ __launch_bounds__(256) void pack_feat_all(
    const float* __restrict__ feat,
    short* __restrict__ featAh, short* __restrict__ featAl,
    short* __restrict__ stg, float* __restrict__ featpart)
{
    __shared__ float lds[32][260];   // pad 260: 16B-aligned rows
    const int tid = threadIdx.x;
    const int kc  = blockIdx.x;   // 0..63 (32-row chunk == kt32)
    const int b   = blockIdx.y;

#pragma unroll
    for (int i = 0; i < 8; ++i) {
        const int lin = i * 256 + tid;
        const int r = lin >> 6, c4 = (lin & 63) * 4;
        float4 v = *(const float4*)&feat[((size_t)b * T_ + kc * 32 + r) * F_ + c4];
        lds[r][c4 + 0] = v.x; lds[r][c4 + 1] = v.y;
        lds[r][c4 + 2] = v.z; lds[r][c4 + 3] = v.w;
    }
    __syncthreads();

    const int lane = tid & 63, w = tid >> 6;
    const int quad = lane >> 4, l15 = lane & 15;

    // (a) A-fragments: 16 tiles (r16h 0..1, fc 0..7), 4 per wave
#pragma unroll
    for (int i = 0; i < 4; ++i) {
        const int idx = w * 4 + i;
        const int r16h = idx >> 3, fc = idx & 7;
        float v[8];
        *(float4*)&v[0] = *(const float4*)&lds[r16h * 16 + l15][fc * 32 + quad * 8];
        *(float4*)&v[4] = *(const float4*)&lds[r16h * 16 + l15][fc * 32 + quad * 8 + 4];
        short8 h, l;
#pragma unroll
        for (int j = 0; j < 8; ++j) {
            const short hh = f2bf(v[j]);
            h[j] = hh; l[j] = f2bf(v[j] - bf2f(hh));
        }
        const int r16 = b * 128 + kc * 2 + r16h;
        const size_t dst = ((size_t)r16 * 8 + fc) * 512 + lane * 8;
        *(short8*)&featAh[dst] = h;
        *(short8*)&featAl[dst] = l;
    }

    // (b) PV B-fragments (f-major, transposed) into stg
#pragma unroll
    for (int fi = 0; fi < 4; ++fi) {
        const int ft = w + fi * 4;
        short8 h;
#pragma unroll
        for (int j = 0; j < 8; ++j)
            h[j] = f2bf(lds[quad * 8 + j][ft * 16 + l15]);
        const size_t dst = ((size_t)(b * 64 + kc)) * 16384 + 8192 + ft * 512 + lane * 8;
        *(short8*)&stg[dst] = h;
    }

    // (c) column sums of this 32-row chunk
    {
        float s = 0.f;
#pragma unroll
        for (int r = 0; r < 32; ++r) s += lds[r][tid];
        featpart[((size_t)b * 64 + kc) * 256 + tid] = s;
    }
}

// ---------------------------------------------------------------------------
// Kernel 2: Wq (hi+lo) / Wk (hi) -> B-fragment order. 64 blocks x 256 thr.
// ---------------------------------------------------------------------------
__global__ __launch_bounds__(256) void pack_w(
    const float* __restrict__ Wq, const float* __restrict__ Wk,
    short* __restrict__ wfqh, short* __restrict__ wfql,
    short* __restrict__ wfkh)
{
    const int tid = threadIdx.x, lane = tid & 63, w = tid >> 6;
    const int idx = blockIdx.x * 4 + w;             // 0..255
    const int isk = idx >> 7, nt = (idx >> 3) & 15, fc = idx & 7;
    const int quad = lane >> 4, l15 = lane & 15;
    const float* __restrict__ W = isk ? Wk : Wq;
    const int row = nt * 16 + l15, col = fc * 32 + quad * 8;

    float v[8];
    *(float4*)&v[0] = *(const float4*)&W[(size_t)row * F_ + col];
    *(float4*)&v[4] = *(const float4*)&W[(size_t)row * F_ + col + 4];
    const size_t dst = ((size_t)(nt * 8 + fc)) * 512 + lane * 8;
    if (isk) {
        short8 h;
#pragma unroll
        for (int j = 0; j < 8; ++j) h[j] = f2bf(v[j]);
        *(short8*)&wfkh[dst] = h;
    } else {
        short8 h, l;
#pragma unroll
        for (int j = 0; j < 8; ++j) {
            const short hh = f2bf(v[j]);
            h[j] = hh; l[j] = f2bf(v[j] - bf2f(hh));
        }
        *(short8*)&wfqh[dst] = h;
        *(short8*)&wfql[dst] = l;
    }
}

// ---------------------------------------------------------------------------
// Kernel 3: per-batch: featbar -> kbar = Wk@featbar + bk -> w = Wq^T kbar,
// c = bq . kbar. Also writes hlens. 8 blocks x 256 thr.
// ---------------------------------------------------------------------------
__global__ __launch_bounds__(256) void wvec_kernel(
    const float* __restrict__ featpart,
    const float* __restrict__ Wq, const float* __restrict__ bq,
    const float* __restrict__ Wk, const float* __restrict__ bk,
    float* __restrict__ wv, float* __restrict__ cv,
    float* __restrict__ out_hlens)
{
    __shared__ float fb[256];
    __shared__ float kb[256];
    const int b = blockIdx.x, tid = threadIdx.x;

    float s = 0.f;
#pragma unroll 8
    for (int c = 0; c < 64; ++c) s += featpart[((size_t)b * 64 + c) * 256 + tid];
    fb[tid] = s * (1.0f / (float)T_);
    __syncthreads();

    float acc = bk[tid];
#pragma unroll 8
    for (int f = 0; f < 256; ++f) acc += Wk[(size_t)tid * 256 + f] * fb[f];
    kb[tid] = acc;
    __syncthreads();

    float wf_ = 0.f;
#pragma unroll 8
    for (int g = 0; g < 256; ++g) wf_ += Wq[(size_t)g * 256 + tid] * kb[g];
    wv[b * 256 + tid] = wf_;

    __syncthreads();
    fb[tid] = bq[tid] * kb[tid];
    __syncthreads();
    for (int st = 128; st > 0; st >>= 1) {
        if (tid < st) fb[tid] += fb[tid + st];
        __syncthreads();
    }
    if (tid == 0) cv[b] = fb[0];
    if (b == 0 && tid < B_) out_hlens[tid] = (float)T_;
}

// ---------------------------------------------------------------------------
// Kernel 4: score[b][t] = feat[b][t] . w_b + c_b
// ---------------------------------------------------------------------------
__global__ __launch_bounds__(256) void score_kernel(
    const float* __restrict__ feat, const float* __restrict__ wv,
    const float* __restrict__ cv, float* __restrict__ out_score)
{
    __shared__ float wl[256];
    const int tid = threadIdx.x;
    const int b   = blockIdx.x >> 5;
    const int t0s = (blockIdx.x & 31) * 64;
    wl[tid] = wv[b * 256 + tid];
    __syncthreads();

    const int row = t0s + (tid >> 2);
    const int fq  = (tid & 3) * 64;
    const float* fr = &feat[((size_t)b * T_ + row) * F_ + fq];
    float s = 0.f;
#pragma unroll
    for (int i = 0; i < 16; ++i) {
        float4 v = *(const float4*)&fr[i * 4];
        s += v.x * wl[fq + i * 4 + 0] + v.y * wl[fq + i * 4 + 1]
           + v.z * wl[fq + i * 4 + 2] + v.w * wl[fq + i * 4 + 3];
    }
    s += __shfl_xor(s, 1, 64);
    s += __shfl_xor(s, 2, 64);
    if ((tid & 3) == 0) out_score[(size_t)b * T_ + row] = s + cv[b];
}

// ---------------------------------------------------------------------------
// Kernel 5: MFMA projection straight into fragments.
// q = feat@Wq^T + bq (split-3: Ah.Bh + Al.Bh + Ah.Bl -> fp32-grade, then
// hi/lo split into qfh/qfl).  k = feat@Wk^T + bk (split-2: (Ah+Al).Bh —
// k is stored bf16-hi anyway) -> kf part of stg blocks.
// grid 512: x&3 = n-group (0,1: q-halves; 2,3: k-halves), x>>2 = row-group.
// 512 threads = 8 waves, wave w handles r16 = rg*8 + w.
// W fragments DMA-staged per nt, double-buffered. Epilogue transposes the
// MFMA C-layout to A/B-fragment layout via wave-private LDS.
// ---------------------------------------------------------------------------
__global__ __launch_bounds__(512, 4) void proj_mfma(
    const short* __restrict__ featAh, const short* __restrict__ featAl,
    const short* __restrict__ wfqh, const short* __restrict__ wfql,
    const short* __restrict__ wfkh,
    const float* __restrict__ bq, const float* __restrict__ bk,
    short* __restrict__ qfh, short* __restrict__ qfl,
    short* __restrict__ stg)
{
    __shared__ short wbuf[2][8192];   // per nt: hi @0 (8KB), lo @4096 (8KB)
    __shared__ float Tr[8][16][36];   // per-wave C transpose (pad 36: 16B rows)

    const int tid = threadIdx.x, lane = tid & 63, w = tid >> 6;
    const int quad = lane >> 4, l15 = lane & 15;
    const int x  = blockIdx.x;
    const int ng = x & 3, rg = x >> 2;
    const bool isq = ng < 2;
    const int r16 = rg * 8 + w;         // 0..1023
    const int b = r16 >> 7, qt16 = r16 & 127;
    const int ntb = isq ? ng * 8 : (ng - 2) * 8;   // nt base within matrix

    // A fragments for this wave's 16 rows (hi/lo)
    short8 ah[8], al[8];
#pragma unroll
    for (int fc = 0; fc < 8; ++fc) {
        const size_t off = ((size_t)r16 * 8 + fc) * 512 + lane * 8;
        ah[fc] = *(const short8*)&featAh[off];
        al[fc] = *(const short8*)&featAl[off];
    }

    const short* __restrict__ wsh = (isq ? wfqh : wfkh) + (size_t)ntb * 4096;
    const short* __restrict__ wsl = wfql + (size_t)ntb * 4096;
    const float* __restrict__ bias = isq ? bq : bk;

    // prologue DMA: nt-step 0
    cp_g2l_16(wsh + tid * 8, &wbuf[0][tid * 8]);
    if (isq) cp_g2l_16(wsl + tid * 8, &wbuf[0][4096 + tid * 8]);

    int cur = 0;
    for (int i = 0; i < 8; ++i, cur ^= 1) {
        __syncthreads();   // drain DMA for wbuf[cur]; prev readers done

        floatx4 C = (floatx4){0.f, 0.f, 0.f, 0.f};
#pragma unroll
        for (int fc = 0; fc < 8; ++fc) {
            short8 wh = *(const short8*)&wbuf[cur][fc * 512 + lane * 8];
            C = __builtin_amdgcn_mfma_f32_16x16x32_bf16(ah[fc], wh, C, 0, 0, 0);
            C = __builtin_amdgcn_mfma_f32_16x16x32_bf16(al[fc], wh, C, 0, 0, 0);
            if (isq) {
                short8 wl2 = *(const short8*)&wbuf[cur][4096 + fc * 512 + lane * 8];
                C = __builtin_amdgcn_mfma_f32_16x16x32_bf16(ah[fc], wl2, C, 0, 0, 0);
            }
        }

        if (i + 1 < 8) {
            cp_g2l_16(wsh + (size_t)(i + 1) * 4096 + tid * 8,
                      &wbuf[cur ^ 1][tid * 8]);
            if (isq) cp_g2l_16(wsl + (size_t)(i + 1) * 4096 + tid * 8,
                               &wbuf[cur ^ 1][4096 + tid * 8]);
        }

        // bias + stash C into transpose tile (col half = nt parity)
        const int nt = ntb + i;
        const float bv = bias[nt * 16 + l15];
        const int ch = (i & 1) * 16;
#pragma unroll
        for (int r = 0; r < 4; ++r)
            Tr[w][quad * 4 + r][ch + l15] = C[r] + bv;

        if (i & 1) {   // pair complete: read in fragment layout, convert, store
            float v[8];
            *(float4*)&v[0] = *(const float4*)&Tr[w][l15][quad * 8];
            *(float4*)&v[4] = *(const float4*)&Tr[w][l15][quad * 8 + 4];
            const int p = nt >> 1;   // 32-feature chunk 0..7
            if (isq) {
                short8 h, l;
#pragma unroll
                for (int j = 0; j < 8; ++j) {
                    const short hh = f2bf(v[j]);
                    h[j] = hh; l[j] = f2bf(v[j] - bf2f(hh));
                }
                const size_t dst = ((size_t)(b * 8 + p) * 128 + qt16) * 512 + lane * 8;
                *(short8*)&qfh[dst] = h;
                *(short8*)&qfl[dst] = l;
            } else {
                short8 h;
#pragma unroll
                for (int j = 0; j < 8; ++j) h[j] = f2bf(v[j]);
                const size_t dst = ((size_t)(b * 64 + (qt16 >> 1))) * 16384
                                 + (p * 2 + (qt16 & 1)) * 512 + lane * 8;
                *(short8*)&stg[dst] = h;
            }
        }
    }
}

// ---------------------------------------------------------------------------
// Kernel 6: fused flash attention (UNCHANGED from R8).
// ---------------------------------------------------------------------------
__global__ __launch_bounds__(512, 4) void attn_mfma(
    const short* __restrict__ qfh, const short* __restrict__ qfl,
    const short* __restrict__ stg,
    float* __restrict__ o0, float* __restrict__ o1,
    float* __restrict__ lpart)
{
    __shared__ short kbuf[2][16384];   // staged kt block: kf @0, ff @8192
    __shared__ float P_lds[64 * 33];
    __shared__ float l_lds[2][64];

    const int tid  = threadIdx.x;
    const int wave = tid >> 6, lane = tid & 63;
    const int qs   = wave & 3, kh = wave >> 2;
    const int quad = lane >> 4, l15 = lane & 15;

    const int lid  = blockIdx.x;      // 0..511
    const int b    = lid & 7;         // XCD pin: batch -> XCD
    const int qt   = (lid >> 3) & 31;
    const int ks   = lid >> 8;
    const int qt16 = qt * 4 + qs;

    short8 qh[8], ql[8];
#pragma unroll
    for (int fc = 0; fc < 8; ++fc) {
        const size_t off = ((size_t)(b * 8 + fc) * 128 + qt16) * 512 + lane * 8;
        qh[fc] = *(const short8*)&qfh[off];
        ql[fc] = *(const short8*)&qfl[off];
    }

    floatx4 O[8];
#pragma unroll
    for (int i = 0; i < 8; ++i) O[i] = (floatx4){0.f, 0.f, 0.f, 0.f};
    float lsum[4] = {0.f, 0.f, 0.f, 0.f};

    const short* sbase = &stg[(size_t)b * 64 * 16384];
    const int kbeg = ks * 32, kend = kbeg + 32;

    {
        const short* src = sbase + (size_t)kbeg * 16384 + tid * 8;
        short* dst = &kbuf[0][tid * 8];
#pragma unroll
        for (int i = 0; i < 4; ++i)
            cp_g2l_16(src + i * 4096, dst + i * 4096);
    }

    int cur = 0;
    for (int kt = kbeg; kt < kend; ++kt, cur ^= 1) {
        __syncthreads();

        floatx4 Sa = (floatx4){0.f, 0.f, 0.f, 0.f};
        floatx4 Sb = (floatx4){0.f, 0.f, 0.f, 0.f};
#pragma unroll
        for (int fc = 0; fc < 8; ++fc) {
            short8 bh = *(const short8*)&kbuf[cur][(fc * 2 + kh) * 512 + lane * 8];
            Sa = __builtin_amdgcn_mfma_f32_16x16x32_bf16(qh[fc], bh, Sa, 0, 0, 0);
            Sb = __builtin_amdgcn_mfma_f32_16x16x32_bf16(ql[fc], bh, Sb, 0, 0, 0);
        }

#pragma unroll
        for (int r = 0; r < 4; ++r) {
            const float e = __expf(Sa[r] + Sb[r]);
            lsum[r] += e;
            P_lds[(qs * 16 + quad * 4 + r) * 33 + kh * 16 + l15] = e;
        }
        __syncthreads();

        short8 ph, pl;
#pragma unroll
        for (int j = 0; j < 8; ++j) {
            const float p = P_lds[(qs * 16 + l15) * 33 + quad * 8 + j];
            const short hh = f2bf(p);
            ph[j] = hh;
            pl[j] = f2bf(p - bf2f(hh));
        }

        if (kt + 1 < kend) {
            const short* src = sbase + (size_t)(kt + 1) * 16384 + tid * 8;
            short* dst = &kbuf[cur ^ 1][tid * 8];
#pragma unroll
            for (int i = 0; i < 4; ++i)
                cp_g2l_16(src + i * 4096, dst + i * 4096);
        }

#pragma unroll
        for (int ft = 0; ft < 8; ++ft) {
            short8 fh = *(const short8*)&kbuf[cur][8192 + (kh * 8 + ft) * 512 + lane * 8];
            O[ft] = __builtin_amdgcn_mfma_f32_16x16x32_bf16(ph, fh, O[ft], 0, 0, 0);
            O[ft] = __builtin_amdgcn_mfma_f32_16x16x32_bf16(pl, fh, O[ft], 0, 0, 0);
        }
    }

#pragma unroll
    for (int r = 0; r < 4; ++r) {
        lsum[r] += __shfl_xor(lsum[r], 1, 64);
        lsum[r] += __shfl_xor(lsum[r], 2, 64);
        lsum[r] += __shfl_xor(lsum[r], 4, 64);
        lsum[r] += __shfl_xor(lsum[r], 8, 64);
    }
    if (l15 == 0) {
#pragma unroll
        for (int r = 0; r < 4; ++r)
            l_lds[kh][qs * 16 + quad * 4 + r] = lsum[r];
    }
    __syncthreads();

    float* __restrict__ opart = ks ? o1 : o0;
    const size_t row0 = (size_t)b * T_ + qt * 64;

    if (tid < 64)
        __builtin_nontemporal_store(l_lds[0][tid] + l_lds[1][tid],
                                    &lpart[(size_t)ks * M_TOT + row0 + tid]);

#pragma unroll
    for (int r = 0; r < 4; ++r) {
        const int qr = qs * 16 + quad * 4 + r;
#pragma unroll
        for (int ft = 0; ft < 8; ++ft)
            __builtin_nontemporal_store(
                O[ft][r], &opart[(row0 + qr) * F_ + kh * 128 + ft * 16 + l15]);
    }
}

// ---------------------------------------------------------------------------
// Kernel 7: combine split-K partials: out = (O0 + O1) / (l0 + l1)
// ---------------------------------------------------------------------------
__global__ __launch_bounds__(256) void combine_kernel(
    float* __restrict__ out_feat, const float* __restrict__ o1,
    const float* __restrict__ lpart)
{
    const size_t gid = (size_t)blockIdx.x * 256 + threadIdx.x;
    const size_t row = gid >> 6;
    const float inv = 1.0f / (lpart[row] + lpart[M_TOT + row]);
    floatx4 a  = __builtin_nontemporal_load(&((const floatx4*)out_feat)[gid]);
    floatx4 bx = __builtin_nontemporal_load(&((const floatx4*)o1)[gid]);
    a = (a + bx) * inv;
    __builtin_nontemporal_store(a, &((floatx4*)out_feat)[gid]);
}

extern "C" void kernel_launch(void* const* d_in, const int* in_sizes, int n_in,
                              void* d_out, int out_size, void* d_ws, size_t ws_size,
                              hipStream_t stream)
{
    const float* feat = (const float*)d_in[0];
    // d_in[1] = hlens (unused: reference overwrites peaks -> hlens_new = T)
    const float* Wq = (const float*)d_in[2];
    const float* bq = (const float*)d_in[3];
    const float* Wk = (const float*)d_in[4];
    const float* bk = (const float*)d_in[5];

    float* out_feat  = (float*)d_out;                       // [8,2048,256]
    float* out_hlens = out_feat + (size_t)M_TOT * F_;       // [8]
    float* out_score = out_hlens + B_;                      // [8,2048]

    // workspace (~49 MB). featA is dead after proj_mfma and aliased as the
    // split-K O-partial; featpart dead after wvec, aliased as lpart.
    short* featAh = (short*)d_ws;                           // 8 MB
    short* featAl = featAh + (size_t)M_TOT * F_;            // 8 MB
    short* qfh    = featAl + (size_t)M_TOT * F_;            // 8 MB
    short* qfl    = qfh + (size_t)M_TOT * F_;               // 8 MB
    short* stg    = qfl + (size_t)M_TOT * F_;               // 16 MB (kf+ff)
    short* wfqh   = stg + (size_t)2 * M_TOT * F_;           // 128 KB
    short* wfql   = wfqh + 65536;                           // 128 KB
    short* wfkh   = wfql + 65536;                           // 128 KB
    float* featpart = (float*)(wfkh + 65536);               // 512 KB
    float* wv     = featpart + 131072;                      // 8 KB
    float* cv     = wv + 2048;                              // 32 B
    float* o1     = (float*)featAh;   // alias (16 MB region)
    float* lpart  = featpart;         // alias

    dim3 fgrid(64, B_);
    pack_feat_all<<<fgrid, 256, 0, stream>>>(feat, featAh, featAl, stg, featpart);

    pack_w<<<64, 256, 0, stream>>>(Wq, Wk, wfqh, wfql, wfkh);

    wvec_kernel<<<B_, 256, 0, stream>>>(featpart, Wq, bq, Wk, bk, wv, cv, out_hlens);

    score_kernel<<<256, 256, 0, stream>>>(feat, wv, cv, out_score);

    proj_mfma<<<512, 512, 0, stream>>>(featAh, featAl, wfqh, wfql, wfkh,
                                       bq, bk, qfh, qfl, stg);

    attn_mfma<<<512, 512, 0, stream>>>(qfh, qfl, stg, out_feat, o1, lpart);

    combine_kernel<<<M_TOT * F_ / 4 / 256, 256, 0, stream>>>(out_feat, o1, lpart);
}

// Round 10
// 208.956 us; speedup vs baseline: 1.8447x; 1.0567x over previous
//
#include <hip/hip_runtime.h>
#include <math.h>

#define B_ 8
#define T_ 2048
#define F_ 256
#define M_TOT (B_ * T_)   // 16384

typedef __attribute__((ext_vector_type(8))) short short8;
typedef __attribute__((ext_vector_type(4))) float floatx4;

// bf16 round-to-nearest-even helpers (finite inputs only)
__device__ __forceinline__ short f2bf(float x) {
    unsigned u = __float_as_uint(x);
    u += 0x7FFF + ((u >> 16) & 1);
    return (short)(u >> 16);
}
__device__ __forceinline__ float bf2f(short s) {
    return __uint_as_float(((unsigned)(unsigned short)s) << 16);
}

// async global -> LDS copy, 16 B per lane (gfx950 global_load_lds_dwordx4)
__device__ __forceinline__ void cp_g2l_16(const void* g, void* l) {
    __builtin_amdgcn_global_load_lds(
        (const __attribute__((address_space(1))) void*)g,
        (__attribute__((address_space(3))) void*)l, 16, 0, 0);
}

// ---------------------------------------------------------------------------
// Kernel 1: one pass over feat producing
//  (a) A-fragments hi/lo for the projection GEMM (featAh/featAl),
//  (b) PV B-fragments (hi) into the staged attn blocks (stg + 8192),
//  (c) per-(b,32-row-chunk) column sums (featpart, for kbar).
// ---------------------------------------------------------------------------
__global__ __launch_bounds__(256) void pack_feat_all(
    const float* __restrict__ feat,
    short* __restrict__ featAh, short* __restrict__ featAl,
    short* __restrict__ stg, float* __restrict__ featpart)
{
    __shared__ float lds[32][260];
    const int tid = threadIdx.x;
    const int kc  = blockIdx.x;   // 0..63
    const int b   = blockIdx.y;

#pragma unroll
    for (int i = 0; i < 8; ++i) {
        const int lin = i * 256 + tid;
        const int r = lin >> 6, c4 = (lin & 63) * 4;
        float4 v = *(const float4*)&feat[((size_t)b * T_ + kc * 32 + r) * F_ + c4];
        lds[r][c4 + 0] = v.x; lds[r][c4 + 1] = v.y;
        lds[r][c4 + 2] = v.z; lds[r][c4 + 3] = v.w;
    }
    __syncthreads();

    const int lane = tid & 63, w = tid >> 6;
    const int quad = lane >> 4, l15 = lane & 15;

#pragma unroll
    for (int i = 0; i < 4; ++i) {
        const int idx = w * 4 + i;
        const int r16h = idx >> 3, fc = idx & 7;
        float v[8];
        *(float4*)&v[0] = *(const float4*)&lds[r16h * 16 + l15][fc * 32 + quad * 8];
        *(float4*)&v[4] = *(const float4*)&lds[r16h * 16 + l15][fc * 32 + quad * 8 + 4];
        short8 h, l;
#pragma unroll
        for (int j = 0; j < 8; ++j) {
            const short hh = f2bf(v[j]);
            h[j] = hh; l[j] = f2bf(v[j] - bf2f(hh));
        }
        const int r16 = b * 128 + kc * 2 + r16h;
        const size_t dst = ((size_t)r16 * 8 + fc) * 512 + lane * 8;
        *(short8*)&featAh[dst] = h;
        *(short8*)&featAl[dst] = l;
    }

#pragma unroll
    for (int fi = 0; fi < 4; ++fi) {
        const int ft = w + fi * 4;
        short8 h;
#pragma unroll
        for (int j = 0; j < 8; ++j)
            h[j] = f2bf(lds[quad * 8 + j][ft * 16 + l15]);
        const size_t dst = ((size_t)(b * 64 + kc)) * 16384 + 8192 + ft * 512 + lane * 8;
        *(short8*)&stg[dst] = h;
    }

    {
        float s = 0.f;
#pragma unroll
        for (int r = 0; r < 32; ++r) s += lds[r][tid];
        featpart[((size_t)b * 64 + kc) * 256 + tid] = s;
    }
}

// ---------------------------------------------------------------------------
// Kernel 2: Wq (hi+lo) / Wk (hi) -> B-fragment order.
// ---------------------------------------------------------------------------
__global__ __launch_bounds__(256) void pack_w(
    const float* __restrict__ Wq, const float* __restrict__ Wk,
    short* __restrict__ wfqh, short* __restrict__ wfql,
    short* __restrict__ wfkh)
{
    const int tid = threadIdx.x, lane = tid & 63, w = tid >> 6;
    const int idx = blockIdx.x * 4 + w;
    const int isk = idx >> 7, nt = (idx >> 3) & 15, fc = idx & 7;
    const int quad = lane >> 4, l15 = lane & 15;
    const float* __restrict__ W = isk ? Wk : Wq;
    const int row = nt * 16 + l15, col = fc * 32 + quad * 8;

    float v[8];
    *(float4*)&v[0] = *(const float4*)&W[(size_t)row * F_ + col];
    *(float4*)&v[4] = *(const float4*)&W[(size_t)row * F_ + col + 4];
    const size_t dst = ((size_t)(nt * 8 + fc)) * 512 + lane * 8;
    if (isk) {
        short8 h;
#pragma unroll
        for (int j = 0; j < 8; ++j) h[j] = f2bf(v[j]);
        *(short8*)&wfkh[dst] = h;
    } else {
        short8 h, l;
#pragma unroll
        for (int j = 0; j < 8; ++j) {
            const short hh = f2bf(v[j]);
            h[j] = hh; l[j] = f2bf(v[j] - bf2f(hh));
        }
        *(short8*)&wfqh[dst] = h;
        *(short8*)&wfql[dst] = l;
    }
}

// ---------------------------------------------------------------------------
// Kernel 3: per-batch kbar chain -> w vector, c scalar; hlens.
// ---------------------------------------------------------------------------
__global__ __launch_bounds__(256) void wvec_kernel(
    const float* __restrict__ featpart,
    const float* __restrict__ Wq, const float* __restrict__ bq,
    const float* __restrict__ Wk, const float* __restrict__ bk,
    float* __restrict__ wv, float* __restrict__ cv,
    float* __restrict__ out_hlens)
{
    __shared__ float fb[256];
    __shared__ float kb[256];
    const int b = blockIdx.x, tid = threadIdx.x;

    float s = 0.f;
#pragma unroll 8
    for (int c = 0; c < 64; ++c) s += featpart[((size_t)b * 64 + c) * 256 + tid];
    fb[tid] = s * (1.0f / (float)T_);
    __syncthreads();

    float acc = bk[tid];
#pragma unroll 8
    for (int f = 0; f < 256; ++f) acc += Wk[(size_t)tid * 256 + f] * fb[f];
    kb[tid] = acc;
    __syncthreads();

    float wf_ = 0.f;
#pragma unroll 8
    for (int g = 0; g < 256; ++g) wf_ += Wq[(size_t)g * 256 + tid] * kb[g];
    wv[b * 256 + tid] = wf_;

    __syncthreads();
    fb[tid] = bq[tid] * kb[tid];
    __syncthreads();
    for (int st = 128; st > 0; st >>= 1) {
        if (tid < st) fb[tid] += fb[tid + st];
        __syncthreads();
    }
    if (tid == 0) cv[b] = fb[0];
    if (b == 0 && tid < B_) out_hlens[tid] = (float)T_;
}

// ---------------------------------------------------------------------------
// Kernel 4: score[b][t] = feat[b][t] . w_b + c_b
// ---------------------------------------------------------------------------
__global__ __launch_bounds__(256) void score_kernel(
    const float* __restrict__ feat, const float* __restrict__ wv,
    const float* __restrict__ cv, float* __restrict__ out_score)
{
    __shared__ float wl[256];
    const int tid = threadIdx.x;
    const int b   = blockIdx.x >> 5;
    const int t0s = (blockIdx.x & 31) * 64;
    wl[tid] = wv[b * 256 + tid];
    __syncthreads();

    const int row = t0s + (tid >> 2);
    const int fq  = (tid & 3) * 64;
    const float* fr = &feat[((size_t)b * T_ + row) * F_ + fq];
    float s = 0.f;
#pragma unroll
    for (int i = 0; i < 16; ++i) {
        float4 v = *(const float4*)&fr[i * 4];
        s += v.x * wl[fq + i * 4 + 0] + v.y * wl[fq + i * 4 + 1]
           + v.z * wl[fq + i * 4 + 2] + v.w * wl[fq + i * 4 + 3];
    }
    s += __shfl_xor(s, 1, 64);
    s += __shfl_xor(s, 2, 64);
    if ((tid & 3) == 0) out_score[(size_t)b * T_ + row] = s + cv[b];
}

// ---------------------------------------------------------------------------
// Kernel 5: MFMA projection straight into fragments (unchanged from R9).
// ---------------------------------------------------------------------------
__global__ __launch_bounds__(512, 4) void proj_mfma(
    const short* __restrict__ featAh, const short* __restrict__ featAl,
    const short* __restrict__ wfqh, const short* __restrict__ wfql,
    const short* __restrict__ wfkh,
    const float* __restrict__ bq, const float* __restrict__ bk,
    short* __restrict__ qfh, short* __restrict__ qfl,
    short* __restrict__ stg)
{
    __shared__ short wbuf[2][8192];
    __shared__ float Tr[8][16][36];

    const int tid = threadIdx.x, lane = tid & 63, w = tid >> 6;
    const int quad = lane >> 4, l15 = lane & 15;
    const int x  = blockIdx.x;
    const int ng = x & 3, rg = x >> 2;
    const bool isq = ng < 2;
    const int r16 = rg * 8 + w;
    const int b = r16 >> 7, qt16 = r16 & 127;
    const int ntb = isq ? ng * 8 : (ng - 2) * 8;

    short8 ah[8], al[8];
#pragma unroll
    for (int fc = 0; fc < 8; ++fc) {
        const size_t off = ((size_t)r16 * 8 + fc) * 512 + lane * 8;
        ah[fc] = *(const short8*)&featAh[off];
        al[fc] = *(const short8*)&featAl[off];
    }

    const short* __restrict__ wsh = (isq ? wfqh : wfkh) + (size_t)ntb * 4096;
    const short* __restrict__ wsl = wfql + (size_t)ntb * 4096;
    const float* __restrict__ bias = isq ? bq : bk;

    cp_g2l_16(wsh + tid * 8, &wbuf[0][tid * 8]);
    if (isq) cp_g2l_16(wsl + tid * 8, &wbuf[0][4096 + tid * 8]);

    int cur = 0;
    for (int i = 0; i < 8; ++i, cur ^= 1) {
        __syncthreads();

        floatx4 C = (floatx4){0.f, 0.f, 0.f, 0.f};
#pragma unroll
        for (int fc = 0; fc < 8; ++fc) {
            short8 wh = *(const short8*)&wbuf[cur][fc * 512 + lane * 8];
            C = __builtin_amdgcn_mfma_f32_16x16x32_bf16(ah[fc], wh, C, 0, 0, 0);
            C = __builtin_amdgcn_mfma_f32_16x16x32_bf16(al[fc], wh, C, 0, 0, 0);
            if (isq) {
                short8 wl2 = *(const short8*)&wbuf[cur][4096 + fc * 512 + lane * 8];
                C = __builtin_amdgcn_mfma_f32_16x16x32_bf16(ah[fc], wl2, C, 0, 0, 0);
            }
        }

        if (i + 1 < 8) {
            cp_g2l_16(wsh + (size_t)(i + 1) * 4096 + tid * 8,
                      &wbuf[cur ^ 1][tid * 8]);
            if (isq) cp_g2l_16(wsl + (size_t)(i + 1) * 4096 + tid * 8,
                               &wbuf[cur ^ 1][4096 + tid * 8]);
        }

        const int nt = ntb + i;
        const float bv = bias[nt * 16 + l15];
        const int ch = (i & 1) * 16;
#pragma unroll
        for (int r = 0; r < 4; ++r)
            Tr[w][quad * 4 + r][ch + l15] = C[r] + bv;

        if (i & 1) {
            float v[8];
            *(float4*)&v[0] = *(const float4*)&Tr[w][l15][quad * 8];
            *(float4*)&v[4] = *(const float4*)&Tr[w][l15][quad * 8 + 4];
            const int p = nt >> 1;
            if (isq) {
                short8 h, l;
#pragma unroll
                for (int j = 0; j < 8; ++j) {
                    const short hh = f2bf(v[j]);
                    h[j] = hh; l[j] = f2bf(v[j] - bf2f(hh));
                }
                const size_t dst = ((size_t)(b * 8 + p) * 128 + qt16) * 512 + lane * 8;
                *(short8*)&qfh[dst] = h;
                *(short8*)&qfl[dst] = l;
            } else {
                short8 h;
#pragma unroll
                for (int j = 0; j < 8; ++j) h[j] = f2bf(v[j]);
                const size_t dst = ((size_t)(b * 64 + (qt16 >> 1))) * 16384
                                 + (p * 2 + (qt16 & 1)) * 512 + lane * 8;
                *(short8*)&stg[dst] = h;
            }
        }
    }
}

// ---------------------------------------------------------------------------
// Kernel 6: fused flash attention, RESTRUCTURED for 2x A-residency.
// 256 threads = 4 waves: wave = (qp 0..1, fh 0..1). Each wave holds TWO
// q-tiles (32 rows) of qh/ql in registers, so every kf/ff ds_read_b128
// feeds 4 MFMAs (was 2) — halves LDS-BW per MFMA. fh doubles as the
// S-phase 16-key half and the PV-phase 128-f half. P tile padded to 36
// floats/row -> A-layout P reads are ds_read_b128 (was scalar b32).
// kt = 32 keys, DMA double-buffered as in R8/R9. Split-K + XCD pin kept.
// LDS: 64K kbuf + 9.2K P + 0.5K = 73.7 KB -> 2 blocks/CU (8 waves/CU).
// ---------------------------------------------------------------------------
__global__ __launch_bounds__(256, 2) void attn_mfma(
    const short* __restrict__ qfh_g, const short* __restrict__ qfl_g,
    const short* __restrict__ stg,
    float* __restrict__ o0, float* __restrict__ o1,
    float* __restrict__ lpart)
{
    __shared__ short kbuf[2][16384];   // staged kt block: kf @0, ff @8192
    __shared__ float P_lds[64 * 36];   // [q][key], rows padded to 36 floats
    __shared__ float l_lds[2][64];     // [fh][q-row]

    const int tid  = threadIdx.x;
    const int wave = tid >> 6, lane = tid & 63;
    const int qp   = wave & 1, fh = wave >> 1;
    const int quad = lane >> 4, l15 = lane & 15;

    const int lid  = blockIdx.x;      // 0..511
    const int b    = lid & 7;         // XCD pin: batch -> XCD
    const int qt   = (lid >> 3) & 31;
    const int ks   = lid >> 8;

    // persistent Q fragments for TWO q-tiles (A-operand), hi/lo: 128 VGPRs
    short8 qh[2][8], ql[2][8];
#pragma unroll
    for (int t = 0; t < 2; ++t) {
        const int qt16 = qt * 4 + qp * 2 + t;
#pragma unroll
        for (int fc = 0; fc < 8; ++fc) {
            const size_t off = ((size_t)(b * 8 + fc) * 128 + qt16) * 512 + lane * 8;
            qh[t][fc] = *(const short8*)&qfh_g[off];
            ql[t][fc] = *(const short8*)&qfl_g[off];
        }
    }

    floatx4 O[2][8];
#pragma unroll
    for (int t = 0; t < 2; ++t)
#pragma unroll
        for (int i = 0; i < 8; ++i) O[t][i] = (floatx4){0.f, 0.f, 0.f, 0.f};
    float lsum[2][4] = {};

    const short* sbase = &stg[(size_t)b * 64 * 16384];
    const int kbeg = ks * 32, kend = kbeg + 32;

    // prologue DMA: 256 thr x 16 B = 4 KB per round, 8 rounds = 32 KB
    {
        const short* src = sbase + (size_t)kbeg * 16384 + tid * 8;
        short* dst = &kbuf[0][tid * 8];
#pragma unroll
        for (int i = 0; i < 8; ++i)
            cp_g2l_16(src + i * 2048, dst + i * 2048);
    }

    int cur = 0;
    for (int kt = kbeg; kt < kend; ++kt, cur ^= 1) {
        __syncthreads();   // drains DMA for kbuf[cur]; P_lds readers done

        // ---- S: 2 q-tiles x this wave's 16-key half (slot = fh) ----------
        floatx4 Sa[2], Sb[2];
#pragma unroll
        for (int t = 0; t < 2; ++t) {
            Sa[t] = (floatx4){0.f, 0.f, 0.f, 0.f};
            Sb[t] = (floatx4){0.f, 0.f, 0.f, 0.f};
        }
#pragma unroll
        for (int fc = 0; fc < 8; ++fc) {
            short8 bh = *(const short8*)&kbuf[cur][(fc * 2 + fh) * 512 + lane * 8];
#pragma unroll
            for (int t = 0; t < 2; ++t) {
                Sa[t] = __builtin_amdgcn_mfma_f32_16x16x32_bf16(qh[t][fc], bh, Sa[t], 0, 0, 0);
                Sb[t] = __builtin_amdgcn_mfma_f32_16x16x32_bf16(ql[t][fc], bh, Sb[t], 0, 0, 0);
            }
        }

        // ---- exp (max-free) + write P [row][key] -------------------------
#pragma unroll
        for (int t = 0; t < 2; ++t)
#pragma unroll
            for (int r = 0; r < 4; ++r) {
                const float e = __expf(Sa[t][r] + Sb[t][r]);
                lsum[t][r] += e;
                P_lds[((qp * 2 + t) * 16 + quad * 4 + r) * 36 + fh * 16 + l15] = e;
            }
        __syncthreads();

        // ---- read P in A-layout (b128), convert to bf16 hi/lo ------------
        short8 ph[2], pl[2];
#pragma unroll
        for (int t = 0; t < 2; ++t) {
            float pv[8];
            *(float4*)&pv[0] = *(const float4*)&P_lds[((qp * 2 + t) * 16 + l15) * 36 + quad * 8];
            *(float4*)&pv[4] = *(const float4*)&P_lds[((qp * 2 + t) * 16 + l15) * 36 + quad * 8 + 4];
#pragma unroll
            for (int j = 0; j < 8; ++j) {
                const short hh = f2bf(pv[j]);
                ph[t][j] = hh;
                pl[t][j] = f2bf(pv[j] - bf2f(hh));
            }
        }

        // ---- prefetch next kt into the other buffer (overlaps PV) --------
        if (kt + 1 < kend) {
            const short* src = sbase + (size_t)(kt + 1) * 16384 + tid * 8;
            short* dst = &kbuf[cur ^ 1][tid * 8];
#pragma unroll
            for (int i = 0; i < 8; ++i)
                cp_g2l_16(src + i * 2048, dst + i * 2048);
        }

        // ---- O += (ph+pl) . fh  (2 q-tiles x wave's 128-f half) ----------
#pragma unroll
        for (int ft = 0; ft < 8; ++ft) {
            short8 fv = *(const short8*)&kbuf[cur][8192 + (fh * 8 + ft) * 512 + lane * 8];
#pragma unroll
            for (int t = 0; t < 2; ++t) {
                O[t][ft] = __builtin_amdgcn_mfma_f32_16x16x32_bf16(ph[t], fv, O[t][ft], 0, 0, 0);
                O[t][ft] = __builtin_amdgcn_mfma_f32_16x16x32_bf16(pl[t], fv, O[t][ft], 0, 0, 0);
            }
        }
    }

    // ---- l: sum over this wave's 16 key-cols, stash per fh-half ----------
#pragma unroll
    for (int t = 0; t < 2; ++t)
#pragma unroll
        for (int r = 0; r < 4; ++r) {
            lsum[t][r] += __shfl_xor(lsum[t][r], 1, 64);
            lsum[t][r] += __shfl_xor(lsum[t][r], 2, 64);
            lsum[t][r] += __shfl_xor(lsum[t][r], 4, 64);
            lsum[t][r] += __shfl_xor(lsum[t][r], 8, 64);
        }
    if (l15 == 0) {
#pragma unroll
        for (int t = 0; t < 2; ++t)
#pragma unroll
            for (int r = 0; r < 4; ++r)
                l_lds[fh][(qp * 2 + t) * 16 + quad * 4 + r] = lsum[t][r];
    }
    __syncthreads();

    float* __restrict__ opart = ks ? o1 : o0;
    const size_t row0 = (size_t)b * T_ + qt * 64;

    if (tid < 64)
        __builtin_nontemporal_store(l_lds[0][tid] + l_lds[1][tid],
                                    &lpart[(size_t)ks * M_TOT + row0 + tid]);

#pragma unroll
    for (int t = 0; t < 2; ++t)
#pragma unroll
        for (int r = 0; r < 4; ++r) {
            const int qr = (qp * 2 + t) * 16 + quad * 4 + r;
#pragma unroll
            for (int ft = 0; ft < 8; ++ft)
                __builtin_nontemporal_store(
                    O[t][ft][r],
                    &opart[(row0 + qr) * F_ + fh * 128 + ft * 16 + l15]);
        }
}

// ---------------------------------------------------------------------------
// Kernel 7: combine split-K partials: out = (O0 + O1) / (l0 + l1)
// ---------------------------------------------------------------------------
__global__ __launch_bounds__(256) void combine_kernel(
    float* __restrict__ out_feat, const float* __restrict__ o1,
    const float* __restrict__ lpart)
{
    const size_t gid = (size_t)blockIdx.x * 256 + threadIdx.x;
    const size_t row = gid >> 6;
    const float inv = 1.0f / (lpart[row] + lpart[M_TOT + row]);
    floatx4 a  = __builtin_nontemporal_load(&((const floatx4*)out_feat)[gid]);
    floatx4 bx = __builtin_nontemporal_load(&((const floatx4*)o1)[gid]);
    a = (a + bx) * inv;
    __builtin_nontemporal_store(a, &((floatx4*)out_feat)[gid]);
}

extern "C" void kernel_launch(void* const* d_in, const int* in_sizes, int n_in,
                              void* d_out, int out_size, void* d_ws, size_t ws_size,
                              hipStream_t stream)
{
    const float* feat = (const float*)d_in[0];
    // d_in[1] = hlens (unused: reference overwrites peaks -> hlens_new = T)
    const float* Wq = (const float*)d_in[2];
    const float* bq = (const float*)d_in[3];
    const float* Wk = (const float*)d_in[4];
    const float* bk = (const float*)d_in[5];

    float* out_feat  = (float*)d_out;                       // [8,2048,256]
    float* out_hlens = out_feat + (size_t)M_TOT * F_;       // [8]
    float* out_score = out_hlens + B_;                      // [8,2048]

    short* featAh = (short*)d_ws;                           // 8 MB
    short* featAl = featAh + (size_t)M_TOT * F_;            // 8 MB
    short* qfh    = featAl + (size_t)M_TOT * F_;            // 8 MB
    short* qfl    = qfh + (size_t)M_TOT * F_;               // 8 MB
    short* stg    = qfl + (size_t)M_TOT * F_;               // 16 MB (kf+ff)
    short* wfqh   = stg + (size_t)2 * M_TOT * F_;           // 128 KB
    short* wfql   = wfqh + 65536;                           // 128 KB
    short* wfkh   = wfql + 65536;                           // 128 KB
    float* featpart = (float*)(wfkh + 65536);               // 512 KB
    float* wv     = featpart + 131072;                      // 8 KB
    float* cv     = wv + 2048;                              // 32 B
    float* o1     = (float*)featAh;   // alias (16 MB region)
    float* lpart  = featpart;         // alias

    dim3 fgrid(64, B_);
    pack_feat_all<<<fgrid, 256, 0, stream>>>(feat, featAh, featAl, stg, featpart);

    pack_w<<<64, 256, 0, stream>>>(Wq, Wk, wfqh, wfql, wfkh);

    wvec_kernel<<<B_, 256, 0, stream>>>(featpart, Wq, bq, Wk, bk, wv, cv, out_hlens);

    score_kernel<<<256, 256, 0, stream>>>(feat, wv, cv, out_score);

    proj_mfma<<<512, 512, 0, stream>>>(featAh, featAl, wfqh, wfql, wfkh,
                                       bq, bk, qfh, qfl, stg);

    attn_mfma<<<512, 256, 0, stream>>>(qfh, qfl, stg, out_feat, o1, lpart);

    combine_kernel<<<M_TOT * F_ / 4 / 256, 256, 0, stream>>>(out_feat, o1, lpart);
}

// Round 11
// 192.851 us; speedup vs baseline: 1.9987x; 1.0835x over previous
//
#include <hip/hip_runtime.h>
#include <math.h>

#define B_ 8
#define T_ 2048
#define F_ 256
#define M_TOT (B_ * T_)   // 16384

typedef __attribute__((ext_vector_type(8))) short short8;
typedef __attribute__((ext_vector_type(4))) float floatx4;

// bf16 round-to-nearest-even helpers (finite inputs only)
__device__ __forceinline__ short f2bf(float x) {
    unsigned u = __float_as_uint(x);
    u += 0x7FFF + ((u >> 16) & 1);
    return (short)(u >> 16);
}
__device__ __forceinline__ float bf2f(short s) {
    return __uint_as_float(((unsigned)(unsigned short)s) << 16);
}

// async global -> LDS copy, 16 B per lane (gfx950 global_load_lds_dwordx4)
__device__ __forceinline__ void cp_g2l_16(const void* g, void* l) {
    __builtin_amdgcn_global_load_lds(
        (const __attribute__((address_space(1))) void*)g,
        (__attribute__((address_space(3))) void*)l, 16, 0, 0);
}

// ---------------------------------------------------------------------------
// Kernel 1: fused pre-pack. Blocks (0..63, b): one pass over feat producing
//  (a) A-fragments hi/lo for the projection GEMM (featAh/featAl, NT stores),
//  (b) PV B-fragments (hi) into the staged attn blocks (stg + 8192),
//  (c) per-(b,32-row-chunk) column sums (featpart, for kbar).
// Blocks (64, g): pack Wq (hi+lo) / Wk (hi) into B-fragment order (absorbed
// former pack_w kernel — one fewer launch).
// ---------------------------------------------------------------------------
__global__ __launch_bounds__(256) void pack_feat_all(
    const float* __restrict__ feat,
    short* __restrict__ featAh, short* __restrict__ featAl,
    short* __restrict__ stg, float* __restrict__ featpart,
    const float* __restrict__ Wq, const float* __restrict__ Wk,
    short* __restrict__ wfqh, short* __restrict__ wfql,
    short* __restrict__ wfkh)
{
    const int tid = threadIdx.x;
    const int lane = tid & 63, w = tid >> 6;
    const int quad = lane >> 4, l15 = lane & 15;

    if (blockIdx.x == 64) {   // ---- W-pack blocks (8 x 256 thr) ----
#pragma unroll
        for (int i = 0; i < 8; ++i) {
            const int idx = blockIdx.y * 32 + w * 8 + i;   // 0..255
            const int isk = idx >> 7, nt = (idx >> 3) & 15, fc = idx & 7;
            const float* __restrict__ W = isk ? Wk : Wq;
            const int row = nt * 16 + l15, col = fc * 32 + quad * 8;
            float v[8];
            *(float4*)&v[0] = *(const float4*)&W[(size_t)row * F_ + col];
            *(float4*)&v[4] = *(const float4*)&W[(size_t)row * F_ + col + 4];
            const size_t dst = ((size_t)(nt * 8 + fc)) * 512 + lane * 8;
            if (isk) {
                short8 h;
#pragma unroll
                for (int j = 0; j < 8; ++j) h[j] = f2bf(v[j]);
                *(short8*)&wfkh[dst] = h;
            } else {
                short8 h, l;
#pragma unroll
                for (int j = 0; j < 8; ++j) {
                    const short hh = f2bf(v[j]);
                    h[j] = hh; l[j] = f2bf(v[j] - bf2f(hh));
                }
                *(short8*)&wfqh[dst] = h;
                *(short8*)&wfql[dst] = l;
            }
        }
        return;
    }

    __shared__ float lds[32][260];
    const int kc  = blockIdx.x;   // 0..63
    const int b   = blockIdx.y;

#pragma unroll
    for (int i = 0; i < 8; ++i) {
        const int lin = i * 256 + tid;
        const int r = lin >> 6, c4 = (lin & 63) * 4;
        float4 v = *(const float4*)&feat[((size_t)b * T_ + kc * 32 + r) * F_ + c4];
        lds[r][c4 + 0] = v.x; lds[r][c4 + 1] = v.y;
        lds[r][c4 + 2] = v.z; lds[r][c4 + 3] = v.w;
    }
    __syncthreads();

#pragma unroll
    for (int i = 0; i < 4; ++i) {
        const int idx = w * 4 + i;
        const int r16h = idx >> 3, fc = idx & 7;
        float v[8];
        *(float4*)&v[0] = *(const float4*)&lds[r16h * 16 + l15][fc * 32 + quad * 8];
        *(float4*)&v[4] = *(const float4*)&lds[r16h * 16 + l15][fc * 32 + quad * 8 + 4];
        short8 h, l;
#pragma unroll
        for (int j = 0; j < 8; ++j) {
            const short hh = f2bf(v[j]);
            h[j] = hh; l[j] = f2bf(v[j] - bf2f(hh));
        }
        const int r16 = b * 128 + kc * 2 + r16h;
        const size_t dst = ((size_t)r16 * 8 + fc) * 512 + lane * 8;
        __builtin_nontemporal_store(h, (short8*)&featAh[dst]);
        __builtin_nontemporal_store(l, (short8*)&featAl[dst]);
    }

#pragma unroll
    for (int fi = 0; fi < 4; ++fi) {
        const int ft = w + fi * 4;
        short8 h;
#pragma unroll
        for (int j = 0; j < 8; ++j)
            h[j] = f2bf(lds[quad * 8 + j][ft * 16 + l15]);
        const size_t dst = ((size_t)(b * 64 + kc)) * 16384 + 8192 + ft * 512 + lane * 8;
        *(short8*)&stg[dst] = h;
    }

    {
        float s = 0.f;
#pragma unroll
        for (int r = 0; r < 32; ++r) s += lds[r][tid];
        featpart[((size_t)b * 64 + kc) * 256 + tid] = s;
    }
}

// ---------------------------------------------------------------------------
// Kernel 2: per-batch kbar chain -> w vector, c scalar; hlens.
// ---------------------------------------------------------------------------
__global__ __launch_bounds__(256) void wvec_kernel(
    const float* __restrict__ featpart,
    const float* __restrict__ Wq, const float* __restrict__ bq,
    const float* __restrict__ Wk, const float* __restrict__ bk,
    float* __restrict__ wv, float* __restrict__ cv,
    float* __restrict__ out_hlens)
{
    __shared__ float fb[256];
    __shared__ float kb[256];
    const int b = blockIdx.x, tid = threadIdx.x;

    float s = 0.f;
#pragma unroll 8
    for (int c = 0; c < 64; ++c) s += featpart[((size_t)b * 64 + c) * 256 + tid];
    fb[tid] = s * (1.0f / (float)T_);
    __syncthreads();

    float acc = bk[tid];
#pragma unroll 8
    for (int f = 0; f < 256; ++f) acc += Wk[(size_t)tid * 256 + f] * fb[f];
    kb[tid] = acc;
    __syncthreads();

    float wf_ = 0.f;
#pragma unroll 8
    for (int g = 0; g < 256; ++g) wf_ += Wq[(size_t)g * 256 + tid] * kb[g];
    wv[b * 256 + tid] = wf_;

    __syncthreads();
    fb[tid] = bq[tid] * kb[tid];
    __syncthreads();
    for (int st = 128; st > 0; st >>= 1) {
        if (tid < st) fb[tid] += fb[tid + st];
        __syncthreads();
    }
    if (tid == 0) cv[b] = fb[0];
    if (b == 0 && tid < B_) out_hlens[tid] = (float)T_;
}

// ---------------------------------------------------------------------------
// Kernel 3: score[b][t] = feat[b][t] . w_b + c_b
// ---------------------------------------------------------------------------
__global__ __launch_bounds__(256) void score_kernel(
    const float* __restrict__ feat, const float* __restrict__ wv,
    const float* __restrict__ cv, float* __restrict__ out_score)
{
    __shared__ float wl[256];
    const int tid = threadIdx.x;
    const int b   = blockIdx.x >> 5;
    const int t0s = (blockIdx.x & 31) * 64;
    wl[tid] = wv[b * 256 + tid];
    __syncthreads();

    const int row = t0s + (tid >> 2);
    const int fq  = (tid & 3) * 64;
    const float* fr = &feat[((size_t)b * T_ + row) * F_ + fq];
    float s = 0.f;
#pragma unroll
    for (int i = 0; i < 16; ++i) {
        float4 v = *(const float4*)&fr[i * 4];
        s += v.x * wl[fq + i * 4 + 0] + v.y * wl[fq + i * 4 + 1]
           + v.z * wl[fq + i * 4 + 2] + v.w * wl[fq + i * 4 + 3];
    }
    s += __shfl_xor(s, 1, 64);
    s += __shfl_xor(s, 2, 64);
    if ((tid & 3) == 0) out_score[(size_t)b * T_ + row] = s + cv[b];
}

// ---------------------------------------------------------------------------
// Kernel 4: MFMA projection straight into fragments (NT stores on outputs).
// ---------------------------------------------------------------------------
__global__ __launch_bounds__(512, 4) void proj_mfma(
    const short* __restrict__ featAh, const short* __restrict__ featAl,
    const short* __restrict__ wfqh, const short* __restrict__ wfql,
    const short* __restrict__ wfkh,
    const float* __restrict__ bq, const float* __restrict__ bk,
    short* __restrict__ qfh, short* __restrict__ qfl,
    short* __restrict__ stg)
{
    __shared__ short wbuf[2][8192];
    __shared__ float Tr[8][16][36];

    const int tid = threadIdx.x, lane = tid & 63, w = tid >> 6;
    const int quad = lane >> 4, l15 = lane & 15;
    const int x  = blockIdx.x;
    const int ng = x & 3, rg = x >> 2;
    const bool isq = ng < 2;
    const int r16 = rg * 8 + w;
    const int b = r16 >> 7, qt16 = r16 & 127;
    const int ntb = isq ? ng * 8 : (ng - 2) * 8;

    short8 ah[8], al[8];
#pragma unroll
    for (int fc = 0; fc < 8; ++fc) {
        const size_t off = ((size_t)r16 * 8 + fc) * 512 + lane * 8;
        ah[fc] = *(const short8*)&featAh[off];
        al[fc] = *(const short8*)&featAl[off];
    }

    const short* __restrict__ wsh = (isq ? wfqh : wfkh) + (size_t)ntb * 4096;
    const short* __restrict__ wsl = wfql + (size_t)ntb * 4096;
    const float* __restrict__ bias = isq ? bq : bk;

    cp_g2l_16(wsh + tid * 8, &wbuf[0][tid * 8]);
    if (isq) cp_g2l_16(wsl + tid * 8, &wbuf[0][4096 + tid * 8]);

    int cur = 0;
    for (int i = 0; i < 8; ++i, cur ^= 1) {
        __syncthreads();

        floatx4 C = (floatx4){0.f, 0.f, 0.f, 0.f};
#pragma unroll
        for (int fc = 0; fc < 8; ++fc) {
            short8 wh = *(const short8*)&wbuf[cur][fc * 512 + lane * 8];
            C = __builtin_amdgcn_mfma_f32_16x16x32_bf16(ah[fc], wh, C, 0, 0, 0);
            C = __builtin_amdgcn_mfma_f32_16x16x32_bf16(al[fc], wh, C, 0, 0, 0);
            if (isq) {
                short8 wl2 = *(const short8*)&wbuf[cur][4096 + fc * 512 + lane * 8];
                C = __builtin_amdgcn_mfma_f32_16x16x32_bf16(ah[fc], wl2, C, 0, 0, 0);
            }
        }

        if (i + 1 < 8) {
            cp_g2l_16(wsh + (size_t)(i + 1) * 4096 + tid * 8,
                      &wbuf[cur ^ 1][tid * 8]);
            if (isq) cp_g2l_16(wsl + (size_t)(i + 1) * 4096 + tid * 8,
                               &wbuf[cur ^ 1][4096 + tid * 8]);
        }

        const int nt = ntb + i;
        const float bv = bias[nt * 16 + l15];
        const int ch = (i & 1) * 16;
#pragma unroll
        for (int r = 0; r < 4; ++r)
            Tr[w][quad * 4 + r][ch + l15] = C[r] + bv;

        if (i & 1) {
            float v[8];
            *(float4*)&v[0] = *(const float4*)&Tr[w][l15][quad * 8];
            *(float4*)&v[4] = *(const float4*)&Tr[w][l15][quad * 8 + 4];
            const int p = nt >> 1;
            if (isq) {
                short8 h, l;
#pragma unroll
                for (int j = 0; j < 8; ++j) {
                    const short hh = f2bf(v[j]);
                    h[j] = hh; l[j] = f2bf(v[j] - bf2f(hh));
                }
                const size_t dst = ((size_t)(b * 8 + p) * 128 + qt16) * 512 + lane * 8;
                __builtin_nontemporal_store(h, (short8*)&qfh[dst]);
                __builtin_nontemporal_store(l, (short8*)&qfl[dst]);
            } else {
                short8 h;
#pragma unroll
                for (int j = 0; j < 8; ++j) h[j] = f2bf(v[j]);
                const size_t dst = ((size_t)(b * 64 + (qt16 >> 1))) * 16384
                                 + (p * 2 + (qt16 & 1)) * 512 + lane * 8;
                *(short8*)&stg[dst] = h;
            }
        }
    }
}

// ---------------------------------------------------------------------------
// Kernel 5: fused flash attention. As R10 (2x A-residency, 4 waves) but PV
// is SPLIT-1: O += bf16(P) . fh only. Error analysis: S-phase k-hi bf16 is
// already the dominant error (~3% P perturbation); P-lo contributed only
// ~0.2% rel on O. Deletes 16 of 48 MFMAs per wave-kt and the pl conversion
// chain (~40 VALU/thread-kt).
// ---------------------------------------------------------------------------
__global__ __launch_bounds__(256, 2) void attn_mfma(
    const short* __restrict__ qfh_g, const short* __restrict__ qfl_g,
    const short* __restrict__ stg,
    float* __restrict__ o0, float* __restrict__ o1,
    float* __restrict__ lpart)
{
    __shared__ short kbuf[2][16384];   // staged kt block: kf @0, ff @8192
    __shared__ float P_lds[64 * 36];   // [q][key], rows padded to 36 floats
    __shared__ float l_lds[2][64];     // [fh][q-row]

    const int tid  = threadIdx.x;
    const int wave = tid >> 6, lane = tid & 63;
    const int qp   = wave & 1, fh = wave >> 1;
    const int quad = lane >> 4, l15 = lane & 15;

    const int lid  = blockIdx.x;      // 0..511
    const int b    = lid & 7;         // XCD pin: batch -> XCD
    const int qt   = (lid >> 3) & 31;
    const int ks   = lid >> 8;

    // persistent Q fragments for TWO q-tiles (A-operand), hi/lo: 128 VGPRs
    short8 qh[2][8], ql[2][8];
#pragma unroll
    for (int t = 0; t < 2; ++t) {
        const int qt16 = qt * 4 + qp * 2 + t;
#pragma unroll
        for (int fc = 0; fc < 8; ++fc) {
            const size_t off = ((size_t)(b * 8 + fc) * 128 + qt16) * 512 + lane * 8;
            qh[t][fc] = *(const short8*)&qfh_g[off];
            ql[t][fc] = *(const short8*)&qfl_g[off];
        }
    }

    floatx4 O[2][8];
#pragma unroll
    for (int t = 0; t < 2; ++t)
#pragma unroll
        for (int i = 0; i < 8; ++i) O[t][i] = (floatx4){0.f, 0.f, 0.f, 0.f};
    float lsum[2][4] = {};

    const short* sbase = &stg[(size_t)b * 64 * 16384];
    const int kbeg = ks * 32, kend = kbeg + 32;

    {
        const short* src = sbase + (size_t)kbeg * 16384 + tid * 8;
        short* dst = &kbuf[0][tid * 8];
#pragma unroll
        for (int i = 0; i < 8; ++i)
            cp_g2l_16(src + i * 2048, dst + i * 2048);
    }

    int cur = 0;
    for (int kt = kbeg; kt < kend; ++kt, cur ^= 1) {
        __syncthreads();   // drains DMA for kbuf[cur]; P_lds readers done

        // ---- S: 2 q-tiles x this wave's 16-key half (slot = fh) ----------
        floatx4 Sa[2], Sb[2];
#pragma unroll
        for (int t = 0; t < 2; ++t) {
            Sa[t] = (floatx4){0.f, 0.f, 0.f, 0.f};
            Sb[t] = (floatx4){0.f, 0.f, 0.f, 0.f};
        }
#pragma unroll
        for (int fc = 0; fc < 8; ++fc) {
            short8 bh = *(const short8*)&kbuf[cur][(fc * 2 + fh) * 512 + lane * 8];
#pragma unroll
            for (int t = 0; t < 2; ++t) {
                Sa[t] = __builtin_amdgcn_mfma_f32_16x16x32_bf16(qh[t][fc], bh, Sa[t], 0, 0, 0);
                Sb[t] = __builtin_amdgcn_mfma_f32_16x16x32_bf16(ql[t][fc], bh, Sb[t], 0, 0, 0);
            }
        }

        // ---- exp (max-free) + write P [row][key] -------------------------
#pragma unroll
        for (int t = 0; t < 2; ++t)
#pragma unroll
            for (int r = 0; r < 4; ++r) {
                const float e = __expf(Sa[t][r] + Sb[t][r]);
                lsum[t][r] += e;
                P_lds[((qp * 2 + t) * 16 + quad * 4 + r) * 36 + fh * 16 + l15] = e;
            }
        __syncthreads();

        // ---- read P in A-layout (b128), convert to bf16 (hi only) --------
        short8 ph[2];
#pragma unroll
        for (int t = 0; t < 2; ++t) {
            float pv[8];
            *(float4*)&pv[0] = *(const float4*)&P_lds[((qp * 2 + t) * 16 + l15) * 36 + quad * 8];
            *(float4*)&pv[4] = *(const float4*)&P_lds[((qp * 2 + t) * 16 + l15) * 36 + quad * 8 + 4];
#pragma unroll
            for (int j = 0; j < 8; ++j)
                ph[t][j] = f2bf(pv[j]);
        }

        // ---- prefetch next kt into the other buffer (overlaps PV) --------
        if (kt + 1 < kend) {
            const short* src = sbase + (size_t)(kt + 1) * 16384 + tid * 8;
            short* dst = &kbuf[cur ^ 1][tid * 8];
#pragma unroll
            for (int i = 0; i < 8; ++i)
                cp_g2l_16(src + i * 2048, dst + i * 2048);
        }

        // ---- O += bf16(P) . fh  (2 q-tiles x wave's 128-f half) ----------
#pragma unroll
        for (int ft = 0; ft < 8; ++ft) {
            short8 fv = *(const short8*)&kbuf[cur][8192 + (fh * 8 + ft) * 512 + lane * 8];
#pragma unroll
            for (int t = 0; t < 2; ++t)
                O[t][ft] = __builtin_amdgcn_mfma_f32_16x16x32_bf16(ph[t], fv, O[t][ft], 0, 0, 0);
        }
    }

    // ---- l: sum over this wave's 16 key-cols, stash per fh-half ----------
#pragma unroll
    for (int t = 0; t < 2; ++t)
#pragma unroll
        for (int r = 0; r < 4; ++r) {
            lsum[t][r] += __shfl_xor(lsum[t][r], 1, 64);
            lsum[t][r] += __shfl_xor(lsum[t][r], 2, 64);
            lsum[t][r] += __shfl_xor(lsum[t][r], 4, 64);
            lsum[t][r] += __shfl_xor(lsum[t][r], 8, 64);
        }
    if (l15 == 0) {
#pragma unroll
        for (int t = 0; t < 2; ++t)
#pragma unroll
            for (int r = 0; r < 4; ++r)
                l_lds[fh][(qp * 2 + t) * 16 + quad * 4 + r] = lsum[t][r];
    }
    __syncthreads();

    float* __restrict__ opart = ks ? o1 : o0;
    const size_t row0 = (size_t)b * T_ + qt * 64;

    if (tid < 64)
        __builtin_nontemporal_store(l_lds[0][tid] + l_lds[1][tid],
                                    &lpart[(size_t)ks * M_TOT + row0 + tid]);

#pragma unroll
    for (int t = 0; t < 2; ++t)
#pragma unroll
        for (int r = 0; r < 4; ++r) {
            const int qr = (qp * 2 + t) * 16 + quad * 4 + r;
#pragma unroll
            for (int ft = 0; ft < 8; ++ft)
                __builtin_nontemporal_store(
                    O[t][ft][r],
                    &opart[(row0 + qr) * F_ + fh * 128 + ft * 16 + l15]);
        }
}

// ---------------------------------------------------------------------------
// Kernel 6: combine split-K partials: out = (O0 + O1) / (l0 + l1)
// ---------------------------------------------------------------------------
__global__ __launch_bounds__(256) void combine_kernel(
    float* __restrict__ out_feat, const float* __restrict__ o1,
    const float* __restrict__ lpart)
{
    const size_t gid = (size_t)blockIdx.x * 256 + threadIdx.x;
    const size_t row = gid >> 6;
    const float inv = 1.0f / (lpart[row] + lpart[M_TOT + row]);
    floatx4 a  = __builtin_nontemporal_load(&((const floatx4*)out_feat)[gid]);
    floatx4 bx = __builtin_nontemporal_load(&((const floatx4*)o1)[gid]);
    a = (a + bx) * inv;
    __builtin_nontemporal_store(a, &((floatx4*)out_feat)[gid]);
}

extern "C" void kernel_launch(void* const* d_in, const int* in_sizes, int n_in,
                              void* d_out, int out_size, void* d_ws, size_t ws_size,
                              hipStream_t stream)
{
    const float* feat = (const float*)d_in[0];
    // d_in[1] = hlens (unused: reference overwrites peaks -> hlens_new = T)
    const float* Wq = (const float*)d_in[2];
    const float* bq = (const float*)d_in[3];
    const float* Wk = (const float*)d_in[4];
    const float* bk = (const float*)d_in[5];

    float* out_feat  = (float*)d_out;                       // [8,2048,256]
    float* out_hlens = out_feat + (size_t)M_TOT * F_;       // [8]
    float* out_score = out_hlens + B_;                      // [8,2048]

    short* featAh = (short*)d_ws;                           // 8 MB
    short* featAl = featAh + (size_t)M_TOT * F_;            // 8 MB
    short* qfh    = featAl + (size_t)M_TOT * F_;            // 8 MB
    short* qfl    = qfh + (size_t)M_TOT * F_;               // 8 MB
    short* stg    = qfl + (size_t)M_TOT * F_;               // 16 MB (kf+ff)
    short* wfqh   = stg + (size_t)2 * M_TOT * F_;           // 128 KB
    short* wfql   = wfqh + 65536;                           // 128 KB
    short* wfkh   = wfql + 65536;                           // 128 KB
    float* featpart = (float*)(wfkh + 65536);               // 512 KB
    float* wv     = featpart + 131072;                      // 8 KB
    float* cv     = wv + 2048;                              // 32 B
    float* o1     = (float*)featAh;   // alias (16 MB region)
    float* lpart  = featpart;         // alias

    dim3 fgrid(65, B_);
    pack_feat_all<<<fgrid, 256, 0, stream>>>(feat, featAh, featAl, stg, featpart,
                                             Wq, Wk, wfqh, wfql, wfkh);

    wvec_kernel<<<B_, 256, 0, stream>>>(featpart, Wq, bq, Wk, bk, wv, cv, out_hlens);

    score_kernel<<<256, 256, 0, stream>>>(feat, wv, cv, out_score);

    proj_mfma<<<512, 512, 0, stream>>>(featAh, featAl, wfqh, wfql, wfkh,
                                       bq, bk, qfh, qfl, stg);

    attn_mfma<<<512, 256, 0, stream>>>(qfh, qfl, stg, out_feat, o1, lpart);

    combine_kernel<<<M_TOT * F_ / 4 / 256, 256, 0, stream>>>(out_feat, o1, lpart);
}